// Round 5
// baseline (915.068 us; speedup 1.0000x reference)
//
#include <hip/hip_runtime.h>

constexpr int NN  = 100000;   // nodes
constexpr int NE  = 1600000;  // edges
constexpr int HID = 32;
constexpr int NPB = 128;                      // nodes per bucket (= 1<<7)
constexpr int NBIN = (NN + NPB - 1) / NPB;    // 782 buckets
constexpr int NB  = (NN + 255) / 256;         // 391

// ---------------- bucket build ----------------

// per-bucket edge histogram (LDS-aggregated, then flushed)
__global__ __launch_bounds__(256) void k_binhist(const int* __restrict__ ei,
                                                 int* __restrict__ bincnt) {
  __shared__ int lh[NBIN];
  int t = threadIdx.x;
  for (int b = t; b < NBIN; b += 256) lh[b] = 0;
  __syncthreads();
  for (int e = blockIdx.x * 256 + t; e < NE; e += gridDim.x * 256)
    atomicAdd(&lh[ei[NE + e] >> 7], 1);
  __syncthreads();
  for (int b = t; b < NBIN; b += 256) {
    int v = lh[b];
    if (v) atomicAdd(&bincnt[b], v);
  }
}

// exclusive scan of 782 bucket counts (single block)
__global__ __launch_bounds__(1024) void k_binscan(const int* __restrict__ bincnt,
                                                  int* __restrict__ binptr,
                                                  int* __restrict__ cursor) {
  __shared__ int s[1024];
  int t = threadIdx.x;
  int v = (t < NBIN) ? bincnt[t] : 0;
  s[t] = v;
  __syncthreads();
#pragma unroll
  for (int off = 1; off < 1024; off <<= 1) {
    int add = (t >= off) ? s[t - off] : 0;
    __syncthreads();
    s[t] += add;
    __syncthreads();
  }
  if (t < NBIN) {
    int ex = s[t] - v;
    binptr[t] = ex;
    cursor[t] = ex;
  }
  if (t == NBIN - 1) binptr[NBIN] = s[t];
}

// scatter packed (src | local_dst<<17) into bucket regions
__global__ __launch_bounds__(256) void k_binscatter(const int* __restrict__ ei,
                                                    int* __restrict__ cursor,
                                                    int* __restrict__ be) {
  int e = blockIdx.x * 256 + threadIdx.x;
  if (e >= NE) return;
  int s = ei[e], d = ei[NE + e];
  int pos = atomicAdd(&cursor[d >> 7], 1);
  be[pos] = s | ((d & (NPB - 1)) << 17);
}

// per-bucket in-degree -> dinv = rsqrt(deg+1)
__global__ __launch_bounds__(256) void k_bindeg(const int* __restrict__ binptr,
                                                const int* __restrict__ be,
                                                float* __restrict__ dinv) {
  __shared__ int ldeg[NPB];
  int t = threadIdx.x, b = blockIdx.x;
  if (t < NPB) ldeg[t] = 0;
  __syncthreads();
  int e0 = binptr[b], e1 = binptr[b + 1];
  for (int k = e0 + t; k < e1; k += 256) atomicAdd(&ldeg[be[k] >> 17], 1);
  __syncthreads();
  int i = b * NPB + t;
  if (t < NPB && i < NN) dinv[i] = rsqrtf((float)ldeg[t] + 1.0f);
}

// ---------------- layers ----------------

// layer 1: per-bucket LDS aggregation of 2-feature x, then 2x32 matvec+LN+relu
__global__ __launch_bounds__(256) void k_l1(const int* __restrict__ binptr,
                                            const int* __restrict__ be,
                                            const float* __restrict__ dinv,
                                            const float* __restrict__ x,
                                            const float* __restrict__ w1,
                                            const float* __restrict__ b1,
                                            const float* __restrict__ g1,
                                            const float* __restrict__ be1,
                                            float* __restrict__ h1) {
  __shared__ float agg[NPB * 2];
  __shared__ float w1s[64], b1s[32], g1s[32], be1s[32];
  int t = threadIdx.x, b = blockIdx.x;
  agg[t] = 0.0f;                       // NPB*2 == 256
  if (t < 64) w1s[t] = w1[t];
  if (t < 32) { b1s[t] = b1[t]; g1s[t] = g1[t]; be1s[t] = be1[t]; }
  __syncthreads();
  const float2* x2 = (const float2*)x;
  int e0 = binptr[b], e1 = binptr[b + 1];
  for (int k = e0 + t; k < e1; k += 256) {
    int v = be[k];
    int s = v & 0x1FFFF, l = v >> 17;
    float ds = dinv[s];
    float2 xv = x2[s];
    atomicAdd(&agg[l * 2],     ds * xv.x);
    atomicAdd(&agg[l * 2 + 1], ds * xv.y);
  }
  __syncthreads();
  int i = b * NPB + t;
  if (t >= NPB || i >= NN) return;
  float di = dinv[i];
  float2 xs = x2[i];
  float a0 = (fmaf(di, xs.x, agg[t * 2]))     * di;
  float a1 = (fmaf(di, xs.y, agg[t * 2 + 1])) * di;
  float h[HID];
  float mu = 0.f;
#pragma unroll
  for (int j = 0; j < HID; j++) {
    h[j] = fmaf(a0, w1s[j], fmaf(a1, w1s[32 + j], b1s[j]));
    mu += h[j];
  }
  mu *= (1.0f / HID);
  float var = 0.f;
#pragma unroll
  for (int j = 0; j < HID; j++) { float dd = h[j] - mu; var += dd * dd; }
  var *= (1.0f / HID);
  float rstd = rsqrtf(var + 1e-5f);
  float4* o4 = (float4*)(h1 + (size_t)i * HID);
#pragma unroll
  for (int q = 0; q < 8; q++) {
    float4 v;
    v.x = fmaxf(fmaf((h[4 * q]     - mu) * rstd, g1s[4 * q],     be1s[4 * q]),     0.f);
    v.y = fmaxf(fmaf((h[4 * q + 1] - mu) * rstd, g1s[4 * q + 1], be1s[4 * q + 1]), 0.f);
    v.z = fmaxf(fmaf((h[4 * q + 2] - mu) * rstd, g1s[4 * q + 2], be1s[4 * q + 2]), 0.f);
    v.w = fmaxf(fmaf((h[4 * q + 3] - mu) * rstd, g1s[4 * q + 3], be1s[4 * q + 3]), 0.f);
    o4[q] = v;
  }
}

// layer 2: per-bucket. Edge phase: 32-lane groups gather h1 (128B coalesced)
// and LDS-atomic into agg[128][32]. Node phase: in-register matvec via shfl,
// LN, relu, w3 projection -> p.
__global__ __launch_bounds__(256) void k_l2(const int* __restrict__ binptr,
                                            const int* __restrict__ be,
                                            const float* __restrict__ dinv,
                                            const float* __restrict__ h1,
                                            const float* __restrict__ w2,
                                            const float* __restrict__ b2,
                                            const float* __restrict__ g2,
                                            const float* __restrict__ be2,
                                            const float* __restrict__ w3,
                                            float* __restrict__ p) {
  __shared__ float agg[NPB * HID];     // 16 KB
  __shared__ float w2s[HID * HID];     // 4 KB
  __shared__ float b2s[32], g2s[32], be2s[32], w3s[32];
  __shared__ int ebuf[256];
  int t = threadIdx.x, b = blockIdx.x;
  for (int u = t; u < NPB * HID; u += 256) agg[u] = 0.0f;
  for (int u = t; u < HID * HID; u += 256) w2s[u] = w2[u];
  if (t < 32) { b2s[t] = b2[t]; g2s[t] = g2[t]; be2s[t] = be2[t]; w3s[t] = w3[t]; }
  int g = t >> 5, f = t & 31;
  int e0 = binptr[b], e1 = binptr[b + 1];
  for (int chunk = e0; chunk < e1; chunk += 256) {
    int m = min(256, e1 - chunk);
    __syncthreads();                   // agg/w2s ready (first iter); prev ebuf consumed
    if (t < m) ebuf[t] = be[chunk + t];
    __syncthreads();
    for (int k = g; k < m; k += 8) {
      int v = ebuf[k];
      int s = v & 0x1FFFF, l = v >> 17;
      float ds = dinv[s];                              // broadcast
      float hv = h1[(size_t)s * HID + f];              // 128B coalesced gather
      atomicAdd(&agg[l * HID + f], ds * hv);           // bank f, conflict-free
    }
  }
  __syncthreads();
  int base = b * NPB;
  for (int n = g; n < NPB; n += 8) {
    int i = base + n;
    if (i >= NN) continue;
    float di = dinv[i];
    float acc = fmaf(di, h1[(size_t)i * HID + f], agg[n * HID + f]) * di;
    float h = b2s[f];
#pragma unroll
    for (int k = 0; k < HID; k++) {
      float ak = __shfl(acc, k, 32);
      h = fmaf(ak, w2s[k * HID + f], h);
    }
    float mu = h;
#pragma unroll
    for (int off = 16; off > 0; off >>= 1) mu += __shfl_xor(mu, off, 32);
    mu *= (1.0f / HID);
    float dd = h - mu;
    float var = dd * dd;
#pragma unroll
    for (int off = 16; off > 0; off >>= 1) var += __shfl_xor(var, off, 32);
    var *= (1.0f / HID);
    float rstd = rsqrtf(var + 1e-5f);
    float v = fmaf(dd * rstd, g2s[f], be2s[f]);
    v = fmaxf(v, 0.0f);
    float pi = v * w3s[f];
#pragma unroll
    for (int off = 16; off > 0; off >>= 1) pi += __shfl_xor(pi, off, 32);
    if (f == 0) p[i] = pi;
  }
}

// layer 3: per-bucket, 1 feature
__global__ __launch_bounds__(256) void k_l3(const int* __restrict__ binptr,
                                            const int* __restrict__ be,
                                            const float* __restrict__ dinv,
                                            const float* __restrict__ p,
                                            const float* __restrict__ b3,
                                            float* __restrict__ out) {
  __shared__ float agg[NPB];
  int t = threadIdx.x, b = blockIdx.x;
  if (t < NPB) agg[t] = 0.0f;
  __syncthreads();
  int e0 = binptr[b], e1 = binptr[b + 1];
  for (int k = e0 + t; k < e1; k += 256) {
    int v = be[k];
    int s = v & 0x1FFFF, l = v >> 17;
    atomicAdd(&agg[l], dinv[s] * p[s]);
  }
  __syncthreads();
  int i = b * NPB + t;
  if (t < NPB && i < NN) {
    float di = dinv[i];
    out[i] = fmaf(di, fmaf(di, p[i], agg[t]), b3[0]);
  }
}

// ---------------- launch ----------------

extern "C" void kernel_launch(void* const* d_in, const int* in_sizes, int n_in,
                              void* d_out, int out_size, void* d_ws, size_t ws_size,
                              hipStream_t stream) {
  const float* x   = (const float*)d_in[0];
  const int*   ei  = (const int*)d_in[1];
  const float* w1  = (const float*)d_in[2];
  const float* b1  = (const float*)d_in[3];
  const float* g1  = (const float*)d_in[4];
  const float* be1 = (const float*)d_in[5];
  const float* w2  = (const float*)d_in[6];
  const float* b2  = (const float*)d_in[7];
  const float* g2  = (const float*)d_in[8];
  const float* be2 = (const float*)d_in[9];
  const float* w3  = (const float*)d_in[10];
  const float* b3  = (const float*)d_in[11];
  float* out = (float*)d_out;

  char* wp = (char*)d_ws;
  auto alloc = [&](size_t bytes) {
    char* r = wp;
    wp += (bytes + 255) & ~size_t(255);
    return r;
  };
  int*   bincnt = (int*)alloc((size_t)NBIN * 4);
  int*   binptr = (int*)alloc((size_t)(NBIN + 1) * 4);
  int*   cursor = (int*)alloc((size_t)NBIN * 4);
  float* dinv   = (float*)alloc((size_t)NN * 4);
  int*   bedge  = (int*)alloc((size_t)NE * 4);
  float* h1     = (float*)alloc((size_t)NN * HID * 4);
  float* p      = (float*)alloc((size_t)NN * 4);

  int bE = (NE + 255) / 256;

  hipMemsetAsync(bincnt, 0, (size_t)NBIN * 4, stream);
  k_binhist   <<<NB, 256, 0, stream>>>(ei, bincnt);
  k_binscan   <<<1, 1024, 0, stream>>>(bincnt, binptr, cursor);
  k_binscatter<<<bE, 256, 0, stream>>>(ei, cursor, bedge);
  k_bindeg    <<<NBIN, 256, 0, stream>>>(binptr, bedge, dinv);
  k_l1        <<<NBIN, 256, 0, stream>>>(binptr, bedge, dinv, x, w1, b1, g1, be1, h1);
  k_l2        <<<NBIN, 256, 0, stream>>>(binptr, bedge, dinv, h1, w2, b2, g2, be2, w3, p);
  k_l3        <<<NBIN, 256, 0, stream>>>(binptr, bedge, dinv, p, b3, out);
}

// Round 6
// 619.565 us; speedup vs baseline: 1.4770x; 1.4770x over previous
//
#include <hip/hip_runtime.h>

constexpr int NN  = 100000;   // nodes
constexpr int NE  = 1600000;  // edges
constexpr int HID = 32;
constexpr int NPB = 128;                      // nodes per bucket (= 1<<7)
constexpr int NBIN = (NN + NPB - 1) / NPB;    // 782 buckets
constexpr int NB  = (NN + 255) / 256;         // 391

// ---------------- build: bucket scatter + per-bucket counting sort ----------------

// per-bucket edge histogram (LDS-aggregated, then flushed)
__global__ __launch_bounds__(256) void k_binhist(const int* __restrict__ ei,
                                                 int* __restrict__ bincnt) {
  __shared__ int lh[NBIN];
  int t = threadIdx.x;
  for (int b = t; b < NBIN; b += 256) lh[b] = 0;
  __syncthreads();
  for (int e = blockIdx.x * 256 + t; e < NE; e += gridDim.x * 256)
    atomicAdd(&lh[ei[NE + e] >> 7], 1);
  __syncthreads();
  for (int b = t; b < NBIN; b += 256) {
    int v = lh[b];
    if (v) atomicAdd(&bincnt[b], v);
  }
}

// exclusive scan of 782 bucket counts (single block)
__global__ __launch_bounds__(1024) void k_binscan(const int* __restrict__ bincnt,
                                                  int* __restrict__ binptr,
                                                  int* __restrict__ cursor) {
  __shared__ int s[1024];
  int t = threadIdx.x;
  int v = (t < NBIN) ? bincnt[t] : 0;
  s[t] = v;
  __syncthreads();
#pragma unroll
  for (int off = 1; off < 1024; off <<= 1) {
    int add = (t >= off) ? s[t - off] : 0;
    __syncthreads();
    s[t] += add;
    __syncthreads();
  }
  if (t < NBIN) {
    int ex = s[t] - v;
    binptr[t] = ex;
    cursor[t] = ex;
  }
  if (t == NBIN - 1) binptr[NBIN] = s[t];
}

// scatter packed (src | local_dst<<17) into bucket regions (write-local at 782 tails)
__global__ __launch_bounds__(256) void k_binscatter(const int* __restrict__ ei,
                                                    int* __restrict__ cursor,
                                                    int* __restrict__ be) {
  int e = blockIdx.x * 256 + threadIdx.x;
  if (e >= NE) return;
  int s = ei[e], d = ei[NE + e];
  int pos = atomicAdd(&cursor[d >> 7], 1);
  be[pos] = s | ((d & (NPB - 1)) << 17);
}

// per-bucket counting sort -> exact per-node CSR + deg + rowptr + dinv
__global__ __launch_bounds__(256) void k_sort(const int* __restrict__ binptr,
                                              const int* __restrict__ be,
                                              int* __restrict__ csr,
                                              int* __restrict__ rowptr,
                                              int* __restrict__ deg,
                                              float* __restrict__ dinv) {
  __shared__ int hist[NPB];
  __shared__ int excl[NPB];
  __shared__ int cur[NPB];
  int t = threadIdx.x, b = blockIdx.x;
  int e0 = binptr[b], e1 = binptr[b + 1];
  if (t < NPB) hist[t] = 0;
  __syncthreads();
  for (int k = e0 + t; k < e1; k += 256) atomicAdd(&hist[be[k] >> 17], 1);
  __syncthreads();
  if (t < NPB) excl[t] = hist[t];
  __syncthreads();
#pragma unroll
  for (int off = 1; off < NPB; off <<= 1) {
    int add = 0;
    if (t < NPB && t >= off) add = excl[t - off];
    __syncthreads();
    if (t < NPB) excl[t] += add;
    __syncthreads();
  }
  if (t < NPB) {
    int ex = excl[t] - hist[t];         // exclusive within bucket
    cur[t] = ex;
    int i = b * NPB + t;
    if (i < NN) {
      int dg = hist[t];
      deg[i] = dg;
      rowptr[i] = e0 + ex;
      dinv[i] = rsqrtf((float)dg + 1.0f);
    }
  }
  __syncthreads();
  for (int k = e0 + t; k < e1; k += 256) {
    int v = be[k];
    int pos = atomicAdd(&cur[v >> 17], 1);
    csr[e0 + pos] = v & 0x1FFFF;        // write within this bucket's 8KB region
  }
}

// ---------------- layers ----------------

// layer 1: per-node thread. agg1 = di*(di*x[i] + sum ds*x[s]); 2x32 matvec+LN+relu
__global__ __launch_bounds__(256) void k_l1(const int* __restrict__ rowptr,
                                            const int* __restrict__ deg,
                                            const int* __restrict__ csr,
                                            const float* __restrict__ dinv,
                                            const float* __restrict__ x,
                                            const float* __restrict__ w1,
                                            const float* __restrict__ b1,
                                            const float* __restrict__ g1,
                                            const float* __restrict__ be1,
                                            float* __restrict__ h1) {
  __shared__ float w1s[64], b1s[32], g1s[32], be1s[32];
  int t = threadIdx.x;
  if (t < 64) w1s[t] = w1[t];
  if (t < 32) { b1s[t] = b1[t]; g1s[t] = g1[t]; be1s[t] = be1[t]; }
  __syncthreads();
  int i = blockIdx.x * 256 + t;
  if (i >= NN) return;
  float di = dinv[i];
  const float2* x2 = (const float2*)x;
  float2 xs = x2[i];
  float in0 = di * xs.x, in1 = di * xs.y;
  int r0 = rowptr[i], dg = deg[i];
  for (int k = 0; k < dg; k++) {
    int s = csr[r0 + k];
    float ds = dinv[s];
    float2 xv = x2[s];
    in0 = fmaf(ds, xv.x, in0);
    in1 = fmaf(ds, xv.y, in1);
  }
  float a0 = di * in0, a1 = di * in1;
  float h[HID];
  float mu = 0.f;
#pragma unroll
  for (int j = 0; j < HID; j++) {
    h[j] = fmaf(a0, w1s[j], fmaf(a1, w1s[32 + j], b1s[j]));
    mu += h[j];
  }
  mu *= (1.0f / HID);
  float var = 0.f;
#pragma unroll
  for (int j = 0; j < HID; j++) { float dd = h[j] - mu; var += dd * dd; }
  var *= (1.0f / HID);
  float rstd = rsqrtf(var + 1e-5f);
  float4* o4 = (float4*)(h1 + (size_t)i * HID);
#pragma unroll
  for (int q = 0; q < 8; q++) {
    float4 v;
    v.x = fmaxf(fmaf((h[4 * q]     - mu) * rstd, g1s[4 * q],     be1s[4 * q]),     0.f);
    v.y = fmaxf(fmaf((h[4 * q + 1] - mu) * rstd, g1s[4 * q + 1], be1s[4 * q + 1]), 0.f);
    v.z = fmaxf(fmaf((h[4 * q + 2] - mu) * rstd, g1s[4 * q + 2], be1s[4 * q + 2]), 0.f);
    v.w = fmaxf(fmaf((h[4 * q + 3] - mu) * rstd, g1s[4 * q + 3], be1s[4 * q + 3]), 0.f);
    o4[q] = v;
  }
}

// layer 2: 32 lanes = one node; 8 nodes/block -> 12500 blocks.
// CSR indices + dinv loaded per-lane coalesced, broadcast via shfl.
// Register aggregation, in-register 32x32 matvec via shfl, LN, relu, w3 -> p.
__global__ __launch_bounds__(256) void k_l2(const int* __restrict__ rowptr,
                                            const int* __restrict__ deg,
                                            const int* __restrict__ csr,
                                            const float* __restrict__ dinv,
                                            const float* __restrict__ h1,
                                            const float* __restrict__ w2,
                                            const float* __restrict__ b2,
                                            const float* __restrict__ g2,
                                            const float* __restrict__ be2,
                                            const float* __restrict__ w3,
                                            float* __restrict__ p) {
  __shared__ float w2s[HID * HID];
  __shared__ float b2s[32], g2s[32], be2s[32], w3s[32];
  int t = threadIdx.x;
  for (int u = t; u < HID * HID; u += 256) w2s[u] = w2[u];
  if (t < 32) { b2s[t] = b2[t]; g2s[t] = g2[t]; be2s[t] = be2[t]; w3s[t] = w3[t]; }
  __syncthreads();
  int i = blockIdx.x * 8 + (t >> 5);   // node
  int f = t & 31;                      // feature lane
  if (i >= NN) return;
  float di = dinv[i];
  float acc = di * h1[(size_t)i * HID + f];
  int r0 = rowptr[i], dg = deg[i];
  for (int base = 0; base < dg; base += 32) {
    int kk = base + f;
    int idx = 0;
    float dsv = 0.f;
    if (kk < dg) {
      idx = csr[r0 + kk];              // coalesced: 32 edges per 128B line
      dsv = dinv[idx];
    }
    int m = min(32, dg - base);
    for (int k = 0; k < m; k++) {
      int s = __shfl(idx, k, 32);
      float ds = __shfl(dsv, k, 32);
      acc = fmaf(ds, h1[(size_t)s * HID + f], acc);   // 128B coalesced gather
    }
  }
  acc *= di;                           // agg2[i,f]
  float h = b2s[f];
#pragma unroll
  for (int k = 0; k < HID; k++) {
    float ak = __shfl(acc, k, 32);
    h = fmaf(ak, w2s[k * HID + f], h);
  }
  float mu = h;
#pragma unroll
  for (int off = 16; off > 0; off >>= 1) mu += __shfl_xor(mu, off, 32);
  mu *= (1.0f / HID);
  float dd = h - mu;
  float var = dd * dd;
#pragma unroll
  for (int off = 16; off > 0; off >>= 1) var += __shfl_xor(var, off, 32);
  var *= (1.0f / HID);
  float rstd = rsqrtf(var + 1e-5f);
  float v = fmaf(dd * rstd, g2s[f], be2s[f]);
  v = fmaxf(v, 0.0f);
  float pi = v * w3s[f];
#pragma unroll
  for (int off = 16; off > 0; off >>= 1) pi += __shfl_xor(pi, off, 32);
  if (f == 0) p[i] = pi;
}

// layer 3: per-node thread. out = b3 + di*(di*p[i] + sum ds*p[s])
__global__ __launch_bounds__(256) void k_l3(const int* __restrict__ rowptr,
                                            const int* __restrict__ deg,
                                            const int* __restrict__ csr,
                                            const float* __restrict__ dinv,
                                            const float* __restrict__ p,
                                            const float* __restrict__ b3,
                                            float* __restrict__ out) {
  int i = blockIdx.x * 256 + threadIdx.x;
  if (i >= NN) return;
  float di = dinv[i];
  float inner = di * p[i];
  int r0 = rowptr[i], dg = deg[i];
  for (int k = 0; k < dg; k++) {
    int s = csr[r0 + k];
    inner = fmaf(dinv[s], p[s], inner);
  }
  out[i] = fmaf(di, inner, b3[0]);
}

// ---------------- launch ----------------

extern "C" void kernel_launch(void* const* d_in, const int* in_sizes, int n_in,
                              void* d_out, int out_size, void* d_ws, size_t ws_size,
                              hipStream_t stream) {
  const float* x   = (const float*)d_in[0];
  const int*   ei  = (const int*)d_in[1];
  const float* w1  = (const float*)d_in[2];
  const float* b1  = (const float*)d_in[3];
  const float* g1  = (const float*)d_in[4];
  const float* be1 = (const float*)d_in[5];
  const float* w2  = (const float*)d_in[6];
  const float* b2  = (const float*)d_in[7];
  const float* g2  = (const float*)d_in[8];
  const float* be2 = (const float*)d_in[9];
  const float* w3  = (const float*)d_in[10];
  const float* b3  = (const float*)d_in[11];
  float* out = (float*)d_out;

  char* wp = (char*)d_ws;
  auto alloc = [&](size_t bytes) {
    char* r = wp;
    wp += (bytes + 255) & ~size_t(255);
    return r;
  };
  int*   bincnt = (int*)alloc((size_t)NBIN * 4);
  int*   binptr = (int*)alloc((size_t)(NBIN + 1) * 4);
  int*   cursor = (int*)alloc((size_t)NBIN * 4);
  int*   bedge  = (int*)alloc((size_t)NE * 4);
  int*   csr    = (int*)alloc((size_t)NE * 4);
  int*   rowptr = (int*)alloc((size_t)NN * 4);
  int*   deg    = (int*)alloc((size_t)NN * 4);
  float* dinv   = (float*)alloc((size_t)NN * 4);
  float* h1     = (float*)alloc((size_t)NN * HID * 4);
  float* p      = (float*)alloc((size_t)NN * 4);

  int bE = (NE + 255) / 256;

  hipMemsetAsync(bincnt, 0, (size_t)NBIN * 4, stream);
  k_binhist   <<<NB, 256, 0, stream>>>(ei, bincnt);
  k_binscan   <<<1, 1024, 0, stream>>>(bincnt, binptr, cursor);
  k_binscatter<<<bE, 256, 0, stream>>>(ei, cursor, bedge);
  k_sort      <<<NBIN, 256, 0, stream>>>(binptr, bedge, csr, rowptr, deg, dinv);
  k_l1        <<<NB, 256, 0, stream>>>(rowptr, deg, csr, dinv, x, w1, b1, g1, be1, h1);
  k_l2        <<<(NN + 7) / 8, 256, 0, stream>>>(rowptr, deg, csr, dinv, h1,
                                                 w2, b2, g2, be2, w3, p);
  k_l3        <<<NB, 256, 0, stream>>>(rowptr, deg, csr, dinv, p, b3, out);
}

// Round 7
// 381.496 us; speedup vs baseline: 2.3986x; 1.6240x over previous
//
#include <hip/hip_runtime.h>

constexpr int NN  = 100000;   // nodes
constexpr int NE  = 1600000;  // edges
constexpr int HID = 32;
constexpr int NPB = 128;                      // nodes per bucket (= 1<<7)
constexpr int NBIN = (NN + NPB - 1) / NPB;    // 782 buckets
constexpr int NB  = (NN + 255) / 256;         // 391

constexpr int NPART = 8;                      // XCD partitions
constexpr int PPB   = (NBIN + NPART - 1) / NPART;  // 98 buckets per partition
constexpr int NCHUNK = 60;                    // edge chunks (grid = 480)
constexpr int CAP   = 16;                     // queue entries = 64B flush chunk

// ---------------- build: bucket scatter + per-bucket counting sort ----------------

// per-bucket edge histogram (LDS-aggregated, then flushed)
__global__ __launch_bounds__(256) void k_binhist(const int* __restrict__ ei,
                                                 int* __restrict__ bincnt) {
  __shared__ int lh[NBIN];
  int t = threadIdx.x;
  for (int b = t; b < NBIN; b += 256) lh[b] = 0;
  __syncthreads();
  for (int e = blockIdx.x * 256 + t; e < NE; e += gridDim.x * 256)
    atomicAdd(&lh[ei[NE + e] >> 7], 1);
  __syncthreads();
  for (int b = t; b < NBIN; b += 256) {
    int v = lh[b];
    if (v) atomicAdd(&bincnt[b], v);
  }
}

// exclusive scan of 782 bucket counts (single block)
__global__ __launch_bounds__(1024) void k_binscan(const int* __restrict__ bincnt,
                                                  int* __restrict__ binptr,
                                                  int* __restrict__ cursor) {
  __shared__ int s[1024];
  int t = threadIdx.x;
  int v = (t < NBIN) ? bincnt[t] : 0;
  s[t] = v;
  __syncthreads();
#pragma unroll
  for (int off = 1; off < 1024; off <<= 1) {
    int add = (t >= off) ? s[t - off] : 0;
    __syncthreads();
    s[t] += add;
    __syncthreads();
  }
  if (t < NBIN) {
    int ex = s[t] - v;
    binptr[t] = ex;
    cursor[t] = ex;
  }
  if (t == NBIN - 1) binptr[NBIN] = s[t];
}

// LDS write-combining scatter: block (chunk, partition) streams its edge chunk,
// queues edges of its 98 buckets in LDS, flushes 64B chunks via one cursor
// atomic per 16 edges. Single-writer contiguous stores -> L2-merged writebacks.
__global__ __launch_bounds__(256) void k_wcscatter(const int* __restrict__ ei,
                                                   int* __restrict__ cursor,
                                                   int* __restrict__ be) {
  __shared__ int q[PPB][CAP];
  __shared__ int qn[PPB];
  int t = threadIdx.x;
  int part  = blockIdx.x & (NPART - 1);
  int chunk = blockIdx.x >> 3;
  int b0  = part * PPB;
  int bHi = min(b0 + PPB, NBIN);
  int nb  = bHi - b0;
  for (int b = t; b < nb; b += 256) qn[b] = 0;
  int ce0 = (int)((long long)NE * chunk / NCHUNK);
  int ce1 = (int)((long long)NE * (chunk + 1) / NCHUNK);
  __syncthreads();
  for (int base = ce0; base < ce1; base += 256) {
    int e = base + t;
    int val = 0, lb = 0;
    bool pending = false;
    if (e < ce1) {
      int d = ei[NE + e];
      int bkt = d >> 7;
      if (bkt >= b0 && bkt < bHi) {
        int s = ei[e];
        val = s | ((d & (NPB - 1)) << 17);
        lb = bkt - b0;
        int slot = atomicAdd(&qn[lb], 1);
        if (slot < CAP) q[lb][slot] = val;
        else pending = true;
      }
    }
    for (;;) {
      __syncthreads();
      for (int b = t; b < nb; b += 256) {
        int n = qn[b];
        if (n >= CAP) {
          int pos = atomicAdd(&cursor[b0 + b], CAP);
#pragma unroll
          for (int j = 0; j < CAP; j++) be[pos + j] = q[b][j];
          qn[b] = 0;                   // entries beyond CAP re-insert below
        }
      }
      if (!__syncthreads_or(pending ? 1 : 0)) break;
      if (pending) {
        int slot = atomicAdd(&qn[lb], 1);
        if (slot < CAP) { q[lb][slot] = val; pending = false; }
      }
    }
  }
  // drain partial queues
  for (int b = t; b < nb; b += 256) {
    int n = qn[b];
    if (n > 0) {
      int pos = atomicAdd(&cursor[b0 + b], n);
      for (int j = 0; j < n; j++) be[pos + j] = q[b][j];
    }
  }
}

// per-bucket counting sort -> exact per-node CSR + deg + rowptr + dinv
__global__ __launch_bounds__(256) void k_sort(const int* __restrict__ binptr,
                                              const int* __restrict__ be,
                                              int* __restrict__ csr,
                                              int* __restrict__ rowptr,
                                              int* __restrict__ deg,
                                              float* __restrict__ dinv) {
  __shared__ int hist[NPB];
  __shared__ int excl[NPB];
  __shared__ int cur[NPB];
  int t = threadIdx.x, b = blockIdx.x;
  int e0 = binptr[b], e1 = binptr[b + 1];
  if (t < NPB) hist[t] = 0;
  __syncthreads();
  for (int k = e0 + t; k < e1; k += 256) atomicAdd(&hist[be[k] >> 17], 1);
  __syncthreads();
  if (t < NPB) excl[t] = hist[t];
  __syncthreads();
#pragma unroll
  for (int off = 1; off < NPB; off <<= 1) {
    int add = 0;
    if (t < NPB && t >= off) add = excl[t - off];
    __syncthreads();
    if (t < NPB) excl[t] += add;
    __syncthreads();
  }
  if (t < NPB) {
    int ex = excl[t] - hist[t];         // exclusive within bucket
    cur[t] = ex;
    int i = b * NPB + t;
    if (i < NN) {
      int dg = hist[t];
      deg[i] = dg;
      rowptr[i] = e0 + ex;
      dinv[i] = rsqrtf((float)dg + 1.0f);
    }
  }
  __syncthreads();
  for (int k = e0 + t; k < e1; k += 256) {
    int v = be[k];
    int pos = atomicAdd(&cur[v >> 17], 1);
    csr[e0 + pos] = v & 0x1FFFF;        // write within this bucket's 8KB region
  }
}

// ---------------- layers ----------------

// layer 1: per-node thread. agg1 = di*(di*x[i] + sum ds*x[s]); 2x32 matvec+LN+relu
__global__ __launch_bounds__(256) void k_l1(const int* __restrict__ rowptr,
                                            const int* __restrict__ deg,
                                            const int* __restrict__ csr,
                                            const float* __restrict__ dinv,
                                            const float* __restrict__ x,
                                            const float* __restrict__ w1,
                                            const float* __restrict__ b1,
                                            const float* __restrict__ g1,
                                            const float* __restrict__ be1,
                                            float* __restrict__ h1) {
  __shared__ float w1s[64], b1s[32], g1s[32], be1s[32];
  int t = threadIdx.x;
  if (t < 64) w1s[t] = w1[t];
  if (t < 32) { b1s[t] = b1[t]; g1s[t] = g1[t]; be1s[t] = be1[t]; }
  __syncthreads();
  int i = blockIdx.x * 256 + t;
  if (i >= NN) return;
  float di = dinv[i];
  const float2* x2 = (const float2*)x;
  float2 xs = x2[i];
  float in0 = di * xs.x, in1 = di * xs.y;
  int r0 = rowptr[i], dg = deg[i];
  for (int k = 0; k < dg; k++) {
    int s = csr[r0 + k];
    float ds = dinv[s];
    float2 xv = x2[s];
    in0 = fmaf(ds, xv.x, in0);
    in1 = fmaf(ds, xv.y, in1);
  }
  float a0 = di * in0, a1 = di * in1;
  float h[HID];
  float mu = 0.f;
#pragma unroll
  for (int j = 0; j < HID; j++) {
    h[j] = fmaf(a0, w1s[j], fmaf(a1, w1s[32 + j], b1s[j]));
    mu += h[j];
  }
  mu *= (1.0f / HID);
  float var = 0.f;
#pragma unroll
  for (int j = 0; j < HID; j++) { float dd = h[j] - mu; var += dd * dd; }
  var *= (1.0f / HID);
  float rstd = rsqrtf(var + 1e-5f);
  float4* o4 = (float4*)(h1 + (size_t)i * HID);
#pragma unroll
  for (int q = 0; q < 8; q++) {
    float4 v;
    v.x = fmaxf(fmaf((h[4 * q]     - mu) * rstd, g1s[4 * q],     be1s[4 * q]),     0.f);
    v.y = fmaxf(fmaf((h[4 * q + 1] - mu) * rstd, g1s[4 * q + 1], be1s[4 * q + 1]), 0.f);
    v.z = fmaxf(fmaf((h[4 * q + 2] - mu) * rstd, g1s[4 * q + 2], be1s[4 * q + 2]), 0.f);
    v.w = fmaxf(fmaf((h[4 * q + 3] - mu) * rstd, g1s[4 * q + 3], be1s[4 * q + 3]), 0.f);
    o4[q] = v;
  }
}

// layer 2: 32 lanes = one node; 8 nodes/block -> 12500 blocks.
// CSR indices + dinv loaded per-lane coalesced, broadcast via shfl.
// Register aggregation, in-register 32x32 matvec via shfl, LN, relu, w3 -> p.
__global__ __launch_bounds__(256) void k_l2(const int* __restrict__ rowptr,
                                            const int* __restrict__ deg,
                                            const int* __restrict__ csr,
                                            const float* __restrict__ dinv,
                                            const float* __restrict__ h1,
                                            const float* __restrict__ w2,
                                            const float* __restrict__ b2,
                                            const float* __restrict__ g2,
                                            const float* __restrict__ be2,
                                            const float* __restrict__ w3,
                                            float* __restrict__ p) {
  __shared__ float w2s[HID * HID];
  __shared__ float b2s[32], g2s[32], be2s[32], w3s[32];
  int t = threadIdx.x;
  for (int u = t; u < HID * HID; u += 256) w2s[u] = w2[u];
  if (t < 32) { b2s[t] = b2[t]; g2s[t] = g2[t]; be2s[t] = be2[t]; w3s[t] = w3[t]; }
  __syncthreads();
  int i = blockIdx.x * 8 + (t >> 5);   // node
  int f = t & 31;                      // feature lane
  if (i >= NN) return;
  float di = dinv[i];
  float acc = di * h1[(size_t)i * HID + f];
  int r0 = rowptr[i], dg = deg[i];
  for (int base = 0; base < dg; base += 32) {
    int kk = base + f;
    int idx = 0;
    float dsv = 0.f;
    if (kk < dg) {
      idx = csr[r0 + kk];              // coalesced: 32 edges per 128B line
      dsv = dinv[idx];
    }
    int m = min(32, dg - base);
    for (int k = 0; k < m; k++) {
      int s = __shfl(idx, k, 32);
      float ds = __shfl(dsv, k, 32);
      acc = fmaf(ds, h1[(size_t)s * HID + f], acc);   // 128B coalesced gather
    }
  }
  acc *= di;                           // agg2[i,f]
  float h = b2s[f];
#pragma unroll
  for (int k = 0; k < HID; k++) {
    float ak = __shfl(acc, k, 32);
    h = fmaf(ak, w2s[k * HID + f], h);
  }
  float mu = h;
#pragma unroll
  for (int off = 16; off > 0; off >>= 1) mu += __shfl_xor(mu, off, 32);
  mu *= (1.0f / HID);
  float dd = h - mu;
  float var = dd * dd;
#pragma unroll
  for (int off = 16; off > 0; off >>= 1) var += __shfl_xor(var, off, 32);
  var *= (1.0f / HID);
  float rstd = rsqrtf(var + 1e-5f);
  float v = fmaf(dd * rstd, g2s[f], be2s[f]);
  v = fmaxf(v, 0.0f);
  float pi = v * w3s[f];
#pragma unroll
  for (int off = 16; off > 0; off >>= 1) pi += __shfl_xor(pi, off, 32);
  if (f == 0) p[i] = pi;
}

// layer 3: per-node thread. out = b3 + di*(di*p[i] + sum ds*p[s])
__global__ __launch_bounds__(256) void k_l3(const int* __restrict__ rowptr,
                                            const int* __restrict__ deg,
                                            const int* __restrict__ csr,
                                            const float* __restrict__ dinv,
                                            const float* __restrict__ p,
                                            const float* __restrict__ b3,
                                            float* __restrict__ out) {
  int i = blockIdx.x * 256 + threadIdx.x;
  if (i >= NN) return;
  float di = dinv[i];
  float inner = di * p[i];
  int r0 = rowptr[i], dg = deg[i];
  for (int k = 0; k < dg; k++) {
    int s = csr[r0 + k];
    inner = fmaf(dinv[s], p[s], inner);
  }
  out[i] = fmaf(di, inner, b3[0]);
}

// ---------------- launch ----------------

extern "C" void kernel_launch(void* const* d_in, const int* in_sizes, int n_in,
                              void* d_out, int out_size, void* d_ws, size_t ws_size,
                              hipStream_t stream) {
  const float* x   = (const float*)d_in[0];
  const int*   ei  = (const int*)d_in[1];
  const float* w1  = (const float*)d_in[2];
  const float* b1  = (const float*)d_in[3];
  const float* g1  = (const float*)d_in[4];
  const float* be1 = (const float*)d_in[5];
  const float* w2  = (const float*)d_in[6];
  const float* b2  = (const float*)d_in[7];
  const float* g2  = (const float*)d_in[8];
  const float* be2 = (const float*)d_in[9];
  const float* w3  = (const float*)d_in[10];
  const float* b3  = (const float*)d_in[11];
  float* out = (float*)d_out;

  char* wp = (char*)d_ws;
  auto alloc = [&](size_t bytes) {
    char* r = wp;
    wp += (bytes + 255) & ~size_t(255);
    return r;
  };
  int*   bincnt = (int*)alloc((size_t)NBIN * 4);
  int*   binptr = (int*)alloc((size_t)(NBIN + 1) * 4);
  int*   cursor = (int*)alloc((size_t)NBIN * 4);
  int*   bedge  = (int*)alloc((size_t)NE * 4);
  int*   csr    = (int*)alloc((size_t)NE * 4);
  int*   rowptr = (int*)alloc((size_t)NN * 4);
  int*   deg    = (int*)alloc((size_t)NN * 4);
  float* dinv   = (float*)alloc((size_t)NN * 4);
  float* h1     = (float*)alloc((size_t)NN * HID * 4);
  float* p      = (float*)alloc((size_t)NN * 4);

  hipMemsetAsync(bincnt, 0, (size_t)NBIN * 4, stream);
  k_binhist  <<<NB, 256, 0, stream>>>(ei, bincnt);
  k_binscan  <<<1, 1024, 0, stream>>>(bincnt, binptr, cursor);
  k_wcscatter<<<NCHUNK * NPART, 256, 0, stream>>>(ei, cursor, bedge);
  k_sort     <<<NBIN, 256, 0, stream>>>(binptr, bedge, csr, rowptr, deg, dinv);
  k_l1       <<<NB, 256, 0, stream>>>(rowptr, deg, csr, dinv, x, w1, b1, g1, be1, h1);
  k_l2       <<<(NN + 7) / 8, 256, 0, stream>>>(rowptr, deg, csr, dinv, h1,
                                                w2, b2, g2, be2, w3, p);
  k_l3       <<<NB, 256, 0, stream>>>(rowptr, deg, csr, dinv, p, b3, out);
}

// Round 8
// 285.163 us; speedup vs baseline: 3.2089x; 1.3378x over previous
//
#include <hip/hip_runtime.h>

constexpr int NN  = 100000;   // nodes
constexpr int NE  = 1600000;  // edges
constexpr int NE4 = NE / 4;   // edge quads
constexpr int HID = 32;
constexpr int NPB = 128;                      // nodes per bucket (= 1<<7)
constexpr int NBIN = (NN + NPB - 1) / NPB;    // 782 buckets
constexpr int NB  = (NN + 255) / 256;         // 391

constexpr int NPART = 8;                      // XCD partitions
constexpr int PPB   = (NBIN + NPART - 1) / NPART;  // 98 buckets per partition
constexpr int NCHUNK = 120;                   // edge chunks (grid = 960)
constexpr int CAP   = 16;                     // queue entries = 64B flush chunk
constexpr int QS    = CAP + 1;                // padded stride (bank spread)

// ---------------- build: bucket scatter + per-bucket counting sort ----------------

// per-bucket edge histogram (LDS-aggregated, then flushed); int4-vectorized reads
__global__ __launch_bounds__(256) void k_binhist(const int* __restrict__ ei,
                                                 int* __restrict__ bincnt) {
  __shared__ int lh[NBIN];
  int t = threadIdx.x;
  for (int b = t; b < NBIN; b += 256) lh[b] = 0;
  __syncthreads();
  const int4* d4 = (const int4*)(ei + NE);
  for (int q = blockIdx.x * 256 + t; q < NE4; q += gridDim.x * 256) {
    int4 v = d4[q];
    atomicAdd(&lh[v.x >> 7], 1);
    atomicAdd(&lh[v.y >> 7], 1);
    atomicAdd(&lh[v.z >> 7], 1);
    atomicAdd(&lh[v.w >> 7], 1);
  }
  __syncthreads();
  for (int b = t; b < NBIN; b += 256) {
    int v = lh[b];
    if (v) atomicAdd(&bincnt[b], v);
  }
}

// exclusive scan of 782 bucket counts (single block)
__global__ __launch_bounds__(1024) void k_binscan(const int* __restrict__ bincnt,
                                                  int* __restrict__ binptr,
                                                  int* __restrict__ cursor) {
  __shared__ int s[1024];
  int t = threadIdx.x;
  int v = (t < NBIN) ? bincnt[t] : 0;
  s[t] = v;
  __syncthreads();
#pragma unroll
  for (int off = 1; off < 1024; off <<= 1) {
    int add = (t >= off) ? s[t - off] : 0;
    __syncthreads();
    s[t] += add;
    __syncthreads();
  }
  if (t < NBIN) {
    int ex = s[t] - v;
    binptr[t] = ex;
    cursor[t] = ex;
  }
  if (t == NBIN - 1) binptr[NBIN] = s[t];
}

// LDS write-combining scatter, 4-edge coarsened. Block (chunk, partition)
// streams its quad range, queues in-partition edges in padded LDS queues,
// flushes 64B chunks via one cursor atomic per 16 edges.
__global__ __launch_bounds__(256) void k_wcscatter(const int* __restrict__ ei,
                                                   int* __restrict__ cursor,
                                                   int* __restrict__ be) {
  __shared__ int q[PPB * QS];
  __shared__ int qn[PPB];
  int t = threadIdx.x;
  int part  = blockIdx.x & (NPART - 1);
  int chunk = blockIdx.x >> 3;
  int b0  = part * PPB;
  int bHi = min(b0 + PPB, NBIN);
  int nb  = bHi - b0;
  for (int b = t; b < nb; b += 256) qn[b] = 0;
  int q0 = (int)((long long)NE4 * chunk / NCHUNK);
  int q1 = (int)((long long)NE4 * (chunk + 1) / NCHUNK);
  const int4* d4 = (const int4*)(ei + NE);
  __syncthreads();
  for (int qbase = q0; qbase < q1; qbase += 256) {
    int qi = qbase + t;
    int4 dv = make_int4(-1, -1, -1, -1);
    if (qi < q1) dv = d4[qi];
    int val0 = 0, val1 = 0, val2 = 0, val3 = 0;
    int lb0 = 0, lb1 = 0, lb2 = 0, lb3 = 0;
    unsigned pend = 0;
    {
      int bkt = dv.x >> 7;
      if (dv.x >= 0 && bkt >= b0 && bkt < bHi) {
        val0 = ei[4 * qi + 0] | ((dv.x & (NPB - 1)) << 17);
        lb0 = bkt - b0;
        int slot = atomicAdd(&qn[lb0], 1);
        if (slot < CAP) q[lb0 * QS + slot] = val0; else pend |= 1u;
      }
    }
    {
      int bkt = dv.y >> 7;
      if (dv.y >= 0 && bkt >= b0 && bkt < bHi) {
        val1 = ei[4 * qi + 1] | ((dv.y & (NPB - 1)) << 17);
        lb1 = bkt - b0;
        int slot = atomicAdd(&qn[lb1], 1);
        if (slot < CAP) q[lb1 * QS + slot] = val1; else pend |= 2u;
      }
    }
    {
      int bkt = dv.z >> 7;
      if (dv.z >= 0 && bkt >= b0 && bkt < bHi) {
        val2 = ei[4 * qi + 2] | ((dv.z & (NPB - 1)) << 17);
        lb2 = bkt - b0;
        int slot = atomicAdd(&qn[lb2], 1);
        if (slot < CAP) q[lb2 * QS + slot] = val2; else pend |= 4u;
      }
    }
    {
      int bkt = dv.w >> 7;
      if (dv.w >= 0 && bkt >= b0 && bkt < bHi) {
        val3 = ei[4 * qi + 3] | ((dv.w & (NPB - 1)) << 17);
        lb3 = bkt - b0;
        int slot = atomicAdd(&qn[lb3], 1);
        if (slot < CAP) q[lb3 * QS + slot] = val3; else pend |= 8u;
      }
    }
    for (;;) {
      __syncthreads();
      for (int b = t; b < nb; b += 256) {
        int n = qn[b];
        if (n >= CAP) {
          int pos = atomicAdd(&cursor[b0 + b], CAP);
#pragma unroll
          for (int j = 0; j < CAP; j++) be[pos + j] = q[b * QS + j];
          qn[b] = 0;                   // overflow entries re-insert below
        }
      }
      if (!__syncthreads_or(pend ? 1 : 0)) break;
      if (pend & 1u) {
        int slot = atomicAdd(&qn[lb0], 1);
        if (slot < CAP) { q[lb0 * QS + slot] = val0; pend &= ~1u; }
      }
      if (pend & 2u) {
        int slot = atomicAdd(&qn[lb1], 1);
        if (slot < CAP) { q[lb1 * QS + slot] = val1; pend &= ~2u; }
      }
      if (pend & 4u) {
        int slot = atomicAdd(&qn[lb2], 1);
        if (slot < CAP) { q[lb2 * QS + slot] = val2; pend &= ~4u; }
      }
      if (pend & 8u) {
        int slot = atomicAdd(&qn[lb3], 1);
        if (slot < CAP) { q[lb3 * QS + slot] = val3; pend &= ~8u; }
      }
    }
  }
  // drain partial queues
  for (int b = t; b < nb; b += 256) {
    int n = qn[b];
    if (n > 0) {
      int pos = atomicAdd(&cursor[b0 + b], n);
      for (int j = 0; j < n; j++) be[pos + j] = q[b * QS + j];
    }
  }
}

// per-bucket counting sort -> exact per-node CSR + deg + rowptr + dinv
__global__ __launch_bounds__(256) void k_sort(const int* __restrict__ binptr,
                                              const int* __restrict__ be,
                                              int* __restrict__ csr,
                                              int* __restrict__ rowptr,
                                              int* __restrict__ deg,
                                              float* __restrict__ dinv) {
  __shared__ int hist[NPB];
  __shared__ int excl[NPB];
  __shared__ int cur[NPB];
  int t = threadIdx.x, b = blockIdx.x;
  int e0 = binptr[b], e1 = binptr[b + 1];
  if (t < NPB) hist[t] = 0;
  __syncthreads();
  for (int k = e0 + t; k < e1; k += 256) atomicAdd(&hist[be[k] >> 17], 1);
  __syncthreads();
  if (t < NPB) excl[t] = hist[t];
  __syncthreads();
#pragma unroll
  for (int off = 1; off < NPB; off <<= 1) {
    int add = 0;
    if (t < NPB && t >= off) add = excl[t - off];
    __syncthreads();
    if (t < NPB) excl[t] += add;
    __syncthreads();
  }
  if (t < NPB) {
    int ex = excl[t] - hist[t];         // exclusive within bucket
    cur[t] = ex;
    int i = b * NPB + t;
    if (i < NN) {
      int dg = hist[t];
      deg[i] = dg;
      rowptr[i] = e0 + ex;
      dinv[i] = rsqrtf((float)dg + 1.0f);
    }
  }
  __syncthreads();
  for (int k = e0 + t; k < e1; k += 256) {
    int v = be[k];
    int pos = atomicAdd(&cur[v >> 17], 1);
    csr[e0 + pos] = v & 0x1FFFF;        // write within this bucket's 8KB region
  }
}

// ---------------- layers ----------------

// layer 1: per-node thread. agg1 = di*(di*x[i] + sum ds*x[s]); 2x32 matvec+LN+relu
__global__ __launch_bounds__(256) void k_l1(const int* __restrict__ rowptr,
                                            const int* __restrict__ deg,
                                            const int* __restrict__ csr,
                                            const float* __restrict__ dinv,
                                            const float* __restrict__ x,
                                            const float* __restrict__ w1,
                                            const float* __restrict__ b1,
                                            const float* __restrict__ g1,
                                            const float* __restrict__ be1,
                                            float* __restrict__ h1) {
  __shared__ float w1s[64], b1s[32], g1s[32], be1s[32];
  int t = threadIdx.x;
  if (t < 64) w1s[t] = w1[t];
  if (t < 32) { b1s[t] = b1[t]; g1s[t] = g1[t]; be1s[t] = be1[t]; }
  __syncthreads();
  int i = blockIdx.x * 256 + t;
  if (i >= NN) return;
  float di = dinv[i];
  const float2* x2 = (const float2*)x;
  float2 xs = x2[i];
  float in0 = di * xs.x, in1 = di * xs.y;
  int r0 = rowptr[i], dg = deg[i];
  for (int k = 0; k < dg; k++) {
    int s = csr[r0 + k];
    float ds = dinv[s];
    float2 xv = x2[s];
    in0 = fmaf(ds, xv.x, in0);
    in1 = fmaf(ds, xv.y, in1);
  }
  float a0 = di * in0, a1 = di * in1;
  float h[HID];
  float mu = 0.f;
#pragma unroll
  for (int j = 0; j < HID; j++) {
    h[j] = fmaf(a0, w1s[j], fmaf(a1, w1s[32 + j], b1s[j]));
    mu += h[j];
  }
  mu *= (1.0f / HID);
  float var = 0.f;
#pragma unroll
  for (int j = 0; j < HID; j++) { float dd = h[j] - mu; var += dd * dd; }
  var *= (1.0f / HID);
  float rstd = rsqrtf(var + 1e-5f);
  float4* o4 = (float4*)(h1 + (size_t)i * HID);
#pragma unroll
  for (int q = 0; q < 8; q++) {
    float4 v;
    v.x = fmaxf(fmaf((h[4 * q]     - mu) * rstd, g1s[4 * q],     be1s[4 * q]),     0.f);
    v.y = fmaxf(fmaf((h[4 * q + 1] - mu) * rstd, g1s[4 * q + 1], be1s[4 * q + 1]), 0.f);
    v.z = fmaxf(fmaf((h[4 * q + 2] - mu) * rstd, g1s[4 * q + 2], be1s[4 * q + 2]), 0.f);
    v.w = fmaxf(fmaf((h[4 * q + 3] - mu) * rstd, g1s[4 * q + 3], be1s[4 * q + 3]), 0.f);
    o4[q] = v;
  }
}

// layer 2: 32 lanes = one node; 8 nodes/block -> 12500 blocks.
// CSR indices + dinv loaded per-lane coalesced, broadcast via shfl.
// Register aggregation, in-register 32x32 matvec via shfl, LN, relu, w3 -> p.
__global__ __launch_bounds__(256) void k_l2(const int* __restrict__ rowptr,
                                            const int* __restrict__ deg,
                                            const int* __restrict__ csr,
                                            const float* __restrict__ dinv,
                                            const float* __restrict__ h1,
                                            const float* __restrict__ w2,
                                            const float* __restrict__ b2,
                                            const float* __restrict__ g2,
                                            const float* __restrict__ be2,
                                            const float* __restrict__ w3,
                                            float* __restrict__ p) {
  __shared__ float w2s[HID * HID];
  __shared__ float b2s[32], g2s[32], be2s[32], w3s[32];
  int t = threadIdx.x;
  for (int u = t; u < HID * HID; u += 256) w2s[u] = w2[u];
  if (t < 32) { b2s[t] = b2[t]; g2s[t] = g2[t]; be2s[t] = be2[t]; w3s[t] = w3[t]; }
  __syncthreads();
  int i = blockIdx.x * 8 + (t >> 5);   // node
  int f = t & 31;                      // feature lane
  if (i >= NN) return;
  float di = dinv[i];
  float acc = di * h1[(size_t)i * HID + f];
  int r0 = rowptr[i], dg = deg[i];
  for (int base = 0; base < dg; base += 32) {
    int kk = base + f;
    int idx = 0;
    float dsv = 0.f;
    if (kk < dg) {
      idx = csr[r0 + kk];              // coalesced: 32 edges per 128B line
      dsv = dinv[idx];
    }
    int m = min(32, dg - base);
    for (int k = 0; k < m; k++) {
      int s = __shfl(idx, k, 32);
      float ds = __shfl(dsv, k, 32);
      acc = fmaf(ds, h1[(size_t)s * HID + f], acc);   // 128B coalesced gather
    }
  }
  acc *= di;                           // agg2[i,f]
  float h = b2s[f];
#pragma unroll
  for (int k = 0; k < HID; k++) {
    float ak = __shfl(acc, k, 32);
    h = fmaf(ak, w2s[k * HID + f], h);
  }
  float mu = h;
#pragma unroll
  for (int off = 16; off > 0; off >>= 1) mu += __shfl_xor(mu, off, 32);
  mu *= (1.0f / HID);
  float dd = h - mu;
  float var = dd * dd;
#pragma unroll
  for (int off = 16; off > 0; off >>= 1) var += __shfl_xor(var, off, 32);
  var *= (1.0f / HID);
  float rstd = rsqrtf(var + 1e-5f);
  float v = fmaf(dd * rstd, g2s[f], be2s[f]);
  v = fmaxf(v, 0.0f);
  float pi = v * w3s[f];
#pragma unroll
  for (int off = 16; off > 0; off >>= 1) pi += __shfl_xor(pi, off, 32);
  if (f == 0) p[i] = pi;
}

// layer 3: per-node thread. out = b3 + di*(di*p[i] + sum ds*p[s])
__global__ __launch_bounds__(256) void k_l3(const int* __restrict__ rowptr,
                                            const int* __restrict__ deg,
                                            const int* __restrict__ csr,
                                            const float* __restrict__ dinv,
                                            const float* __restrict__ p,
                                            const float* __restrict__ b3,
                                            float* __restrict__ out) {
  int i = blockIdx.x * 256 + threadIdx.x;
  if (i >= NN) return;
  float di = dinv[i];
  float inner = di * p[i];
  int r0 = rowptr[i], dg = deg[i];
  for (int k = 0; k < dg; k++) {
    int s = csr[r0 + k];
    inner = fmaf(dinv[s], p[s], inner);
  }
  out[i] = fmaf(di, inner, b3[0]);
}

// ---------------- launch ----------------

extern "C" void kernel_launch(void* const* d_in, const int* in_sizes, int n_in,
                              void* d_out, int out_size, void* d_ws, size_t ws_size,
                              hipStream_t stream) {
  const float* x   = (const float*)d_in[0];
  const int*   ei  = (const int*)d_in[1];
  const float* w1  = (const float*)d_in[2];
  const float* b1  = (const float*)d_in[3];
  const float* g1  = (const float*)d_in[4];
  const float* be1 = (const float*)d_in[5];
  const float* w2  = (const float*)d_in[6];
  const float* b2  = (const float*)d_in[7];
  const float* g2  = (const float*)d_in[8];
  const float* be2 = (const float*)d_in[9];
  const float* w3  = (const float*)d_in[10];
  const float* b3  = (const float*)d_in[11];
  float* out = (float*)d_out;

  char* wp = (char*)d_ws;
  auto alloc = [&](size_t bytes) {
    char* r = wp;
    wp += (bytes + 255) & ~size_t(255);
    return r;
  };
  int*   bincnt = (int*)alloc((size_t)NBIN * 4);
  int*   binptr = (int*)alloc((size_t)(NBIN + 1) * 4);
  int*   cursor = (int*)alloc((size_t)NBIN * 4);
  int*   bedge  = (int*)alloc((size_t)NE * 4);
  int*   csr    = (int*)alloc((size_t)NE * 4);
  int*   rowptr = (int*)alloc((size_t)NN * 4);
  int*   deg    = (int*)alloc((size_t)NN * 4);
  float* dinv   = (float*)alloc((size_t)NN * 4);
  float* h1     = (float*)alloc((size_t)NN * HID * 4);
  float* p      = (float*)alloc((size_t)NN * 4);

  hipMemsetAsync(bincnt, 0, (size_t)NBIN * 4, stream);
  k_binhist  <<<NB, 256, 0, stream>>>(ei, bincnt);
  k_binscan  <<<1, 1024, 0, stream>>>(bincnt, binptr, cursor);
  k_wcscatter<<<NCHUNK * NPART, 256, 0, stream>>>(ei, cursor, bedge);
  k_sort     <<<NBIN, 256, 0, stream>>>(binptr, bedge, csr, rowptr, deg, dinv);
  k_l1       <<<NB, 256, 0, stream>>>(rowptr, deg, csr, dinv, x, w1, b1, g1, be1, h1);
  k_l2       <<<(NN + 7) / 8, 256, 0, stream>>>(rowptr, deg, csr, dinv, h1,
                                                w2, b2, g2, be2, w3, p);
  k_l3       <<<NB, 256, 0, stream>>>(rowptr, deg, csr, dinv, p, b3, out);
}

// Round 10
// 271.430 us; speedup vs baseline: 3.3713x; 1.0506x over previous
//
#include <hip/hip_runtime.h>

constexpr int NN  = 100000;   // nodes
constexpr int NE  = 1600000;  // edges
constexpr int NE4 = NE / 4;   // edge quads
constexpr int HID = 32;
constexpr int NPB = 128;                      // nodes per bucket (= 1<<7)
constexpr int NBIN = (NN + NPB - 1) / NPB;    // 782 buckets
constexpr int NB  = (NN + 255) / 256;         // 391

constexpr int NPART = 8;                      // XCD partitions
constexpr int PPB   = (NBIN + NPART - 1) / NPART;  // 98 buckets per partition
constexpr int NCHUNK = 120;                   // edge chunks (grid = 960)
constexpr int CAP   = 16;                     // queue entries = 64B flush chunk
constexpr int QS    = CAP + 1;                // padded stride (bank spread)

// ---------------- build: bucket scatter + per-bucket counting sort ----------------

__global__ __launch_bounds__(256) void k_binhist(const int* __restrict__ ei,
                                                 int* __restrict__ bincnt) {
  __shared__ int lh[NBIN];
  int t = threadIdx.x;
  for (int b = t; b < NBIN; b += 256) lh[b] = 0;
  __syncthreads();
  const int4* d4 = (const int4*)(ei + NE);
  for (int q = blockIdx.x * 256 + t; q < NE4; q += gridDim.x * 256) {
    int4 v = d4[q];
    atomicAdd(&lh[v.x >> 7], 1);
    atomicAdd(&lh[v.y >> 7], 1);
    atomicAdd(&lh[v.z >> 7], 1);
    atomicAdd(&lh[v.w >> 7], 1);
  }
  __syncthreads();
  for (int b = t; b < NBIN; b += 256) {
    int v = lh[b];
    if (v) atomicAdd(&bincnt[b], v);
  }
}

__global__ __launch_bounds__(1024) void k_binscan(const int* __restrict__ bincnt,
                                                  int* __restrict__ binptr,
                                                  int* __restrict__ cursor) {
  __shared__ int s[1024];
  int t = threadIdx.x;
  int v = (t < NBIN) ? bincnt[t] : 0;
  s[t] = v;
  __syncthreads();
#pragma unroll
  for (int off = 1; off < 1024; off <<= 1) {
    int add = (t >= off) ? s[t - off] : 0;
    __syncthreads();
    s[t] += add;
    __syncthreads();
  }
  if (t < NBIN) {
    int ex = s[t] - v;
    binptr[t] = ex;
    cursor[t] = ex;
  }
  if (t == NBIN - 1) binptr[NBIN] = s[t];
}

// LDS write-combining scatter, 4-edge coarsened (see round-7 notes)
__global__ __launch_bounds__(256) void k_wcscatter(const int* __restrict__ ei,
                                                   int* __restrict__ cursor,
                                                   int* __restrict__ be) {
  __shared__ int q[PPB * QS];
  __shared__ int qn[PPB];
  int t = threadIdx.x;
  int part  = blockIdx.x & (NPART - 1);
  int chunk = blockIdx.x >> 3;
  int b0  = part * PPB;
  int bHi = min(b0 + PPB, NBIN);
  int nb  = bHi - b0;
  for (int b = t; b < nb; b += 256) qn[b] = 0;
  int q0 = (int)((long long)NE4 * chunk / NCHUNK);
  int q1 = (int)((long long)NE4 * (chunk + 1) / NCHUNK);
  const int4* d4 = (const int4*)(ei + NE);
  __syncthreads();
  for (int qbase = q0; qbase < q1; qbase += 256) {
    int qi = qbase + t;
    int4 dv = make_int4(-1, -1, -1, -1);
    if (qi < q1) dv = d4[qi];
    int val0 = 0, val1 = 0, val2 = 0, val3 = 0;
    int lb0 = 0, lb1 = 0, lb2 = 0, lb3 = 0;
    unsigned pend = 0;
    {
      int bkt = dv.x >> 7;
      if (dv.x >= 0 && bkt >= b0 && bkt < bHi) {
        val0 = ei[4 * qi + 0] | ((dv.x & (NPB - 1)) << 17);
        lb0 = bkt - b0;
        int slot = atomicAdd(&qn[lb0], 1);
        if (slot < CAP) q[lb0 * QS + slot] = val0; else pend |= 1u;
      }
    }
    {
      int bkt = dv.y >> 7;
      if (dv.y >= 0 && bkt >= b0 && bkt < bHi) {
        val1 = ei[4 * qi + 1] | ((dv.y & (NPB - 1)) << 17);
        lb1 = bkt - b0;
        int slot = atomicAdd(&qn[lb1], 1);
        if (slot < CAP) q[lb1 * QS + slot] = val1; else pend |= 2u;
      }
    }
    {
      int bkt = dv.z >> 7;
      if (dv.z >= 0 && bkt >= b0 && bkt < bHi) {
        val2 = ei[4 * qi + 2] | ((dv.z & (NPB - 1)) << 17);
        lb2 = bkt - b0;
        int slot = atomicAdd(&qn[lb2], 1);
        if (slot < CAP) q[lb2 * QS + slot] = val2; else pend |= 4u;
      }
    }
    {
      int bkt = dv.w >> 7;
      if (dv.w >= 0 && bkt >= b0 && bkt < bHi) {
        val3 = ei[4 * qi + 3] | ((dv.w & (NPB - 1)) << 17);
        lb3 = bkt - b0;
        int slot = atomicAdd(&qn[lb3], 1);
        if (slot < CAP) q[lb3 * QS + slot] = val3; else pend |= 8u;
      }
    }
    for (;;) {
      __syncthreads();
      for (int b = t; b < nb; b += 256) {
        int n = qn[b];
        if (n >= CAP) {
          int pos = atomicAdd(&cursor[b0 + b], CAP);
#pragma unroll
          for (int j = 0; j < CAP; j++) be[pos + j] = q[b * QS + j];
          qn[b] = 0;
        }
      }
      if (!__syncthreads_or(pend ? 1 : 0)) break;
      if (pend & 1u) {
        int slot = atomicAdd(&qn[lb0], 1);
        if (slot < CAP) { q[lb0 * QS + slot] = val0; pend &= ~1u; }
      }
      if (pend & 2u) {
        int slot = atomicAdd(&qn[lb1], 1);
        if (slot < CAP) { q[lb1 * QS + slot] = val1; pend &= ~2u; }
      }
      if (pend & 4u) {
        int slot = atomicAdd(&qn[lb2], 1);
        if (slot < CAP) { q[lb2 * QS + slot] = val2; pend &= ~4u; }
      }
      if (pend & 8u) {
        int slot = atomicAdd(&qn[lb3], 1);
        if (slot < CAP) { q[lb3 * QS + slot] = val3; pend &= ~8u; }
      }
    }
  }
  for (int b = t; b < nb; b += 256) {
    int n = qn[b];
    if (n > 0) {
      int pos = atomicAdd(&cursor[b0 + b], n);
      for (int j = 0; j < n; j++) be[pos + j] = q[b * QS + j];
    }
  }
}

// per-bucket counting sort -> CSR + deg + rowptr + dinv + xs (= dinv*x premult)
__global__ __launch_bounds__(256) void k_sort(const int* __restrict__ binptr,
                                              const int* __restrict__ be,
                                              const float* __restrict__ x,
                                              int* __restrict__ csr,
                                              int* __restrict__ rowptr,
                                              int* __restrict__ deg,
                                              float* __restrict__ dinv,
                                              float* __restrict__ xs) {
  __shared__ int hist[NPB];
  __shared__ int excl[NPB];
  __shared__ int cur[NPB];
  int t = threadIdx.x, b = blockIdx.x;
  int e0 = binptr[b], e1 = binptr[b + 1];
  if (t < NPB) hist[t] = 0;
  __syncthreads();
  for (int k = e0 + t; k < e1; k += 256) atomicAdd(&hist[be[k] >> 17], 1);
  __syncthreads();
  if (t < NPB) excl[t] = hist[t];
  __syncthreads();
#pragma unroll
  for (int off = 1; off < NPB; off <<= 1) {
    int add = 0;
    if (t < NPB && t >= off) add = excl[t - off];
    __syncthreads();
    if (t < NPB) excl[t] += add;
    __syncthreads();
  }
  if (t < NPB) {
    int ex = excl[t] - hist[t];
    cur[t] = ex;
    int i = b * NPB + t;
    if (i < NN) {
      int dg = hist[t];
      deg[i] = dg;
      rowptr[i] = e0 + ex;
      float d = rsqrtf((float)dg + 1.0f);
      dinv[i] = d;
      float2 xv = ((const float2*)x)[i];
      ((float2*)xs)[i] = make_float2(d * xv.x, d * xv.y);
    }
  }
  __syncthreads();
  for (int k = e0 + t; k < e1; k += 256) {
    int v = be[k];
    int pos = atomicAdd(&cur[v >> 17], 1);
    csr[e0 + pos] = v & 0x1FFFF;
  }
}

// ---------------- layers (round-8 structure, premultiplied operands) ----------------

// layer 1: per-node thread. agg1 = di*(xs[i] + sum xs[s]); 2x32 matvec+LN+relu.
// Writes h1s = di * relu(LN(...))  (premultiplied for layer 2)
__global__ __launch_bounds__(256) void k_l1(const int* __restrict__ rowptr,
                                            const int* __restrict__ deg,
                                            const int* __restrict__ csr,
                                            const float* __restrict__ dinv,
                                            const float* __restrict__ xs,
                                            const float* __restrict__ w1,
                                            const float* __restrict__ b1,
                                            const float* __restrict__ g1,
                                            const float* __restrict__ be1,
                                            float* __restrict__ h1s) {
  __shared__ float w1s[64], b1s[32], g1s[32], be1s[32];
  int t = threadIdx.x;
  if (t < 64) w1s[t] = w1[t];
  if (t < 32) { b1s[t] = b1[t]; g1s[t] = g1[t]; be1s[t] = be1[t]; }
  __syncthreads();
  int i = blockIdx.x * 256 + t;
  if (i >= NN) return;
  const float2* xs2 = (const float2*)xs;
  float2 sv = xs2[i];
  float in0 = sv.x, in1 = sv.y;           // self term (xs already has dinv)
  int r0 = rowptr[i], dg = deg[i];
  for (int k = 0; k < dg; k++) {
    int s = csr[r0 + k];
    float2 v = xs2[s];
    in0 += v.x;
    in1 += v.y;
  }
  float di = dinv[i];
  float a0 = di * in0, a1 = di * in1;
  float h[HID];
  float mu = 0.f;
#pragma unroll
  for (int j = 0; j < HID; j++) {
    h[j] = fmaf(a0, w1s[j], fmaf(a1, w1s[32 + j], b1s[j]));
    mu += h[j];
  }
  mu *= (1.0f / HID);
  float var = 0.f;
#pragma unroll
  for (int j = 0; j < HID; j++) { float dd = h[j] - mu; var += dd * dd; }
  var *= (1.0f / HID);
  float rstd = rsqrtf(var + 1e-5f);
  float4* o4 = (float4*)(h1s + (size_t)i * HID);
#pragma unroll
  for (int q = 0; q < 8; q++) {
    float4 v;
    v.x = di * fmaxf(fmaf((h[4 * q]     - mu) * rstd, g1s[4 * q],     be1s[4 * q]),     0.f);
    v.y = di * fmaxf(fmaf((h[4 * q + 1] - mu) * rstd, g1s[4 * q + 1], be1s[4 * q + 1]), 0.f);
    v.z = di * fmaxf(fmaf((h[4 * q + 2] - mu) * rstd, g1s[4 * q + 2], be1s[4 * q + 2]), 0.f);
    v.w = di * fmaxf(fmaf((h[4 * q + 3] - mu) * rstd, g1s[4 * q + 3], be1s[4 * q + 3]), 0.f);
    o4[q] = v;
  }
}

// layer 2: 32 lanes = one node; 8 nodes/block -> 12500 blocks.
// CSR indices loaded per-lane coalesced, broadcast via shfl (idx only; premult
// removed the per-edge dinv). Register aggregation, in-register 32x32 matvec
// via shfl, LN, relu, w3.  Writes ps = dinv[i] * p[i] (premult for layer 3).
__global__ __launch_bounds__(256) void k_l2(const int* __restrict__ rowptr,
                                            const int* __restrict__ deg,
                                            const int* __restrict__ csr,
                                            const float* __restrict__ dinv,
                                            const float* __restrict__ h1s,
                                            const float* __restrict__ w2,
                                            const float* __restrict__ b2,
                                            const float* __restrict__ g2,
                                            const float* __restrict__ be2,
                                            const float* __restrict__ w3,
                                            float* __restrict__ ps) {
  __shared__ float w2s[HID * HID];
  __shared__ float b2s[32], g2s[32], be2s[32], w3s[32];
  int t = threadIdx.x;
  for (int u = t; u < HID * HID; u += 256) w2s[u] = w2[u];
  if (t < 32) { b2s[t] = b2[t]; g2s[t] = g2[t]; be2s[t] = be2[t]; w3s[t] = w3[t]; }
  __syncthreads();
  int i = blockIdx.x * 8 + (t >> 5);   // node (grid exact: 12500*8 == NN)
  int f = t & 31;                      // feature lane
  float acc = h1s[(size_t)i * HID + f];     // self term (premultiplied)
  int r0 = rowptr[i], dg = deg[i];
  for (int base = 0; base < dg; base += 32) {
    int kk = base + f;
    int idx = (kk < dg) ? csr[r0 + kk] : 0;   // coalesced: 32 edges per 128B line
    int m = min(32, dg - base);
    for (int k = 0; k < m; k++) {
      int s = __shfl(idx, k, 32);
      acc += h1s[(size_t)s * HID + f];        // 128B coalesced gather, plain sum
    }
  }
  float di = dinv[i];
  acc *= di;                           // agg2[i,f]
  float h = b2s[f];
#pragma unroll
  for (int k = 0; k < HID; k++) {
    float ak = __shfl(acc, k, 32);
    h = fmaf(ak, w2s[k * HID + f], h);
  }
  float mu = h;
#pragma unroll
  for (int off = 16; off > 0; off >>= 1) mu += __shfl_xor(mu, off, 32);
  mu *= (1.0f / HID);
  float dd = h - mu;
  float var = dd * dd;
#pragma unroll
  for (int off = 16; off > 0; off >>= 1) var += __shfl_xor(var, off, 32);
  var *= (1.0f / HID);
  float rstd = rsqrtf(var + 1e-5f);
  float v = fmaf(dd * rstd, g2s[f], be2s[f]);
  v = fmaxf(v, 0.0f);
  float pi = v * w3s[f];
#pragma unroll
  for (int off = 16; off > 0; off >>= 1) pi += __shfl_xor(pi, off, 32);
  if (f == 0) ps[i] = di * pi;
}

// layer 3: per-node thread; plain sum of premultiplied ps
__global__ __launch_bounds__(256) void k_l3(const int* __restrict__ rowptr,
                                            const int* __restrict__ deg,
                                            const int* __restrict__ csr,
                                            const float* __restrict__ dinv,
                                            const float* __restrict__ ps,
                                            const float* __restrict__ b3,
                                            float* __restrict__ out) {
  int i = blockIdx.x * 256 + threadIdx.x;
  if (i >= NN) return;
  float inner = ps[i];                 // self term (premultiplied)
  int r0 = rowptr[i], dg = deg[i];
  for (int k = 0; k < dg; k++) inner += ps[csr[r0 + k]];
  out[i] = fmaf(dinv[i], inner, b3[0]);
}

// ---------------- launch ----------------

extern "C" void kernel_launch(void* const* d_in, const int* in_sizes, int n_in,
                              void* d_out, int out_size, void* d_ws, size_t ws_size,
                              hipStream_t stream) {
  const float* x   = (const float*)d_in[0];
  const int*   ei  = (const int*)d_in[1];
  const float* w1  = (const float*)d_in[2];
  const float* b1  = (const float*)d_in[3];
  const float* g1  = (const float*)d_in[4];
  const float* be1 = (const float*)d_in[5];
  const float* w2  = (const float*)d_in[6];
  const float* b2  = (const float*)d_in[7];
  const float* g2  = (const float*)d_in[8];
  const float* be2 = (const float*)d_in[9];
  const float* w3  = (const float*)d_in[10];
  const float* b3  = (const float*)d_in[11];
  float* out = (float*)d_out;

  char* wp = (char*)d_ws;
  auto alloc = [&](size_t bytes) {
    char* r = wp;
    wp += (bytes + 255) & ~size_t(255);
    return r;
  };
  int*   bincnt = (int*)alloc((size_t)NBIN * 4);
  int*   binptr = (int*)alloc((size_t)(NBIN + 1) * 4);
  int*   cursor = (int*)alloc((size_t)NBIN * 4);
  int*   bedge  = (int*)alloc((size_t)NE * 4);
  int*   csr    = (int*)alloc((size_t)NE * 4);
  int*   rowptr = (int*)alloc((size_t)NN * 4);
  int*   deg    = (int*)alloc((size_t)NN * 4);
  float* dinv   = (float*)alloc((size_t)NN * 4);
  float* xs     = (float*)alloc((size_t)NN * 2 * 4);
  float* h1s    = (float*)alloc((size_t)NN * HID * 4);
  float* ps     = (float*)alloc((size_t)NN * 4);

  hipMemsetAsync(bincnt, 0, (size_t)NBIN * 4, stream);
  k_binhist  <<<NB, 256, 0, stream>>>(ei, bincnt);
  k_binscan  <<<1, 1024, 0, stream>>>(bincnt, binptr, cursor);
  k_wcscatter<<<NCHUNK * NPART, 256, 0, stream>>>(ei, cursor, bedge);
  k_sort     <<<NBIN, 256, 0, stream>>>(binptr, bedge, x, csr, rowptr, deg, dinv, xs);
  k_l1       <<<NB, 256, 0, stream>>>(rowptr, deg, csr, dinv, xs, w1, b1, g1, be1, h1s);
  k_l2       <<<NN / 8, 256, 0, stream>>>(rowptr, deg, csr, dinv, h1s,
                                          w2, b2, g2, be2, w3, ps);
  k_l3       <<<NB, 256, 0, stream>>>(rowptr, deg, csr, dinv, ps, b3, out);
}

// Round 11
// 239.948 us; speedup vs baseline: 3.8136x; 1.1312x over previous
//
#include <hip/hip_runtime.h>

constexpr int NN  = 100000;   // nodes
constexpr int NE  = 1600000;  // edges
constexpr int NE4 = NE / 4;   // edge quads
constexpr int HID = 32;
constexpr int NPB = 128;                      // nodes per bucket (= 1<<7)
constexpr int NBIN = (NN + NPB - 1) / NPB;    // 782 buckets
constexpr int NB  = (NN + 255) / 256;         // 391

constexpr int NPART = 8;                      // XCD partitions
constexpr int PPB   = (NBIN + NPART - 1) / NPART;  // 98 buckets per partition
constexpr int NCHUNK = 120;                   // edge chunks (grid = 960)
constexpr int CAP   = 16;                     // queue entries = 64B flush chunk
constexpr int QS    = CAP + 1;                // padded stride (bank spread)

// ---------------- build: bucket scatter + per-bucket counting sort ----------------

__global__ __launch_bounds__(256) void k_binhist(const int* __restrict__ ei,
                                                 int* __restrict__ bincnt) {
  __shared__ int lh[NBIN];
  int t = threadIdx.x;
  for (int b = t; b < NBIN; b += 256) lh[b] = 0;
  __syncthreads();
  const int4* d4 = (const int4*)(ei + NE);
  for (int q = blockIdx.x * 256 + t; q < NE4; q += gridDim.x * 256) {
    int4 v = d4[q];
    atomicAdd(&lh[v.x >> 7], 1);
    atomicAdd(&lh[v.y >> 7], 1);
    atomicAdd(&lh[v.z >> 7], 1);
    atomicAdd(&lh[v.w >> 7], 1);
  }
  __syncthreads();
  for (int b = t; b < NBIN; b += 256) {
    int v = lh[b];
    if (v) atomicAdd(&bincnt[b], v);
  }
}

__global__ __launch_bounds__(1024) void k_binscan(const int* __restrict__ bincnt,
                                                  int* __restrict__ binptr,
                                                  int* __restrict__ cursor) {
  __shared__ int s[1024];
  int t = threadIdx.x;
  int v = (t < NBIN) ? bincnt[t] : 0;
  s[t] = v;
  __syncthreads();
#pragma unroll
  for (int off = 1; off < 1024; off <<= 1) {
    int add = (t >= off) ? s[t - off] : 0;
    __syncthreads();
    s[t] += add;
    __syncthreads();
  }
  if (t < NBIN) {
    int ex = s[t] - v;
    binptr[t] = ex;
    cursor[t] = ex;
  }
  if (t == NBIN - 1) binptr[NBIN] = s[t];
}

// LDS write-combining scatter, 4-edge coarsened (see round-7 notes)
__global__ __launch_bounds__(256) void k_wcscatter(const int* __restrict__ ei,
                                                   int* __restrict__ cursor,
                                                   int* __restrict__ be) {
  __shared__ int q[PPB * QS];
  __shared__ int qn[PPB];
  int t = threadIdx.x;
  int part  = blockIdx.x & (NPART - 1);
  int chunk = blockIdx.x >> 3;
  int b0  = part * PPB;
  int bHi = min(b0 + PPB, NBIN);
  int nb  = bHi - b0;
  for (int b = t; b < nb; b += 256) qn[b] = 0;
  int q0 = (int)((long long)NE4 * chunk / NCHUNK);
  int q1 = (int)((long long)NE4 * (chunk + 1) / NCHUNK);
  const int4* d4 = (const int4*)(ei + NE);
  __syncthreads();
  for (int qbase = q0; qbase < q1; qbase += 256) {
    int qi = qbase + t;
    int4 dv = make_int4(-1, -1, -1, -1);
    if (qi < q1) dv = d4[qi];
    int val0 = 0, val1 = 0, val2 = 0, val3 = 0;
    int lb0 = 0, lb1 = 0, lb2 = 0, lb3 = 0;
    unsigned pend = 0;
    {
      int bkt = dv.x >> 7;
      if (dv.x >= 0 && bkt >= b0 && bkt < bHi) {
        val0 = ei[4 * qi + 0] | ((dv.x & (NPB - 1)) << 17);
        lb0 = bkt - b0;
        int slot = atomicAdd(&qn[lb0], 1);
        if (slot < CAP) q[lb0 * QS + slot] = val0; else pend |= 1u;
      }
    }
    {
      int bkt = dv.y >> 7;
      if (dv.y >= 0 && bkt >= b0 && bkt < bHi) {
        val1 = ei[4 * qi + 1] | ((dv.y & (NPB - 1)) << 17);
        lb1 = bkt - b0;
        int slot = atomicAdd(&qn[lb1], 1);
        if (slot < CAP) q[lb1 * QS + slot] = val1; else pend |= 2u;
      }
    }
    {
      int bkt = dv.z >> 7;
      if (dv.z >= 0 && bkt >= b0 && bkt < bHi) {
        val2 = ei[4 * qi + 2] | ((dv.z & (NPB - 1)) << 17);
        lb2 = bkt - b0;
        int slot = atomicAdd(&qn[lb2], 1);
        if (slot < CAP) q[lb2 * QS + slot] = val2; else pend |= 4u;
      }
    }
    {
      int bkt = dv.w >> 7;
      if (dv.w >= 0 && bkt >= b0 && bkt < bHi) {
        val3 = ei[4 * qi + 3] | ((dv.w & (NPB - 1)) << 17);
        lb3 = bkt - b0;
        int slot = atomicAdd(&qn[lb3], 1);
        if (slot < CAP) q[lb3 * QS + slot] = val3; else pend |= 8u;
      }
    }
    for (;;) {
      __syncthreads();
      for (int b = t; b < nb; b += 256) {
        int n = qn[b];
        if (n >= CAP) {
          int pos = atomicAdd(&cursor[b0 + b], CAP);
#pragma unroll
          for (int j = 0; j < CAP; j++) be[pos + j] = q[b * QS + j];
          qn[b] = 0;
        }
      }
      if (!__syncthreads_or(pend ? 1 : 0)) break;
      if (pend & 1u) {
        int slot = atomicAdd(&qn[lb0], 1);
        if (slot < CAP) { q[lb0 * QS + slot] = val0; pend &= ~1u; }
      }
      if (pend & 2u) {
        int slot = atomicAdd(&qn[lb1], 1);
        if (slot < CAP) { q[lb1 * QS + slot] = val1; pend &= ~2u; }
      }
      if (pend & 4u) {
        int slot = atomicAdd(&qn[lb2], 1);
        if (slot < CAP) { q[lb2 * QS + slot] = val2; pend &= ~4u; }
      }
      if (pend & 8u) {
        int slot = atomicAdd(&qn[lb3], 1);
        if (slot < CAP) { q[lb3 * QS + slot] = val3; pend &= ~8u; }
      }
    }
  }
  for (int b = t; b < nb; b += 256) {
    int n = qn[b];
    if (n > 0) {
      int pos = atomicAdd(&cursor[b0 + b], n);
      for (int j = 0; j < n; j++) be[pos + j] = q[b * QS + j];
    }
  }
}

// per-bucket counting sort -> CSR + deg + rowptr + dinv + xs (= dinv*x premult)
__global__ __launch_bounds__(256) void k_sort(const int* __restrict__ binptr,
                                              const int* __restrict__ be,
                                              const float* __restrict__ x,
                                              int* __restrict__ csr,
                                              int* __restrict__ rowptr,
                                              int* __restrict__ deg,
                                              float* __restrict__ dinv,
                                              float* __restrict__ xs) {
  __shared__ int hist[NPB];
  __shared__ int excl[NPB];
  __shared__ int cur[NPB];
  int t = threadIdx.x, b = blockIdx.x;
  int e0 = binptr[b], e1 = binptr[b + 1];
  if (t < NPB) hist[t] = 0;
  __syncthreads();
  for (int k = e0 + t; k < e1; k += 256) atomicAdd(&hist[be[k] >> 17], 1);
  __syncthreads();
  if (t < NPB) excl[t] = hist[t];
  __syncthreads();
#pragma unroll
  for (int off = 1; off < NPB; off <<= 1) {
    int add = 0;
    if (t < NPB && t >= off) add = excl[t - off];
    __syncthreads();
    if (t < NPB) excl[t] += add;
    __syncthreads();
  }
  if (t < NPB) {
    int ex = excl[t] - hist[t];
    cur[t] = ex;
    int i = b * NPB + t;
    if (i < NN) {
      int dg = hist[t];
      deg[i] = dg;
      rowptr[i] = e0 + ex;
      float d = rsqrtf((float)dg + 1.0f);
      dinv[i] = d;
      float2 xv = ((const float2*)x)[i];
      ((float2*)xs)[i] = make_float2(d * xv.x, d * xv.y);
    }
  }
  __syncthreads();
  for (int k = e0 + t; k < e1; k += 256) {
    int v = be[k];
    int pos = atomicAdd(&cur[v >> 17], 1);
    csr[e0 + pos] = v & 0x1FFFF;
  }
}

// ---------------- layers (premultiplied operands) ----------------

// layer 1: per-node thread, 4x-batched gather of xs (order-preserving ILP).
// Writes h1s = di * relu(LN(...))  (premultiplied for layer 2)
__global__ __launch_bounds__(256) void k_l1(const int* __restrict__ rowptr,
                                            const int* __restrict__ deg,
                                            const int* __restrict__ csr,
                                            const float* __restrict__ dinv,
                                            const float* __restrict__ xs,
                                            const float* __restrict__ w1,
                                            const float* __restrict__ b1,
                                            const float* __restrict__ g1,
                                            const float* __restrict__ be1,
                                            float* __restrict__ h1s) {
  __shared__ float w1s[64], b1s[32], g1s[32], be1s[32];
  int t = threadIdx.x;
  if (t < 64) w1s[t] = w1[t];
  if (t < 32) { b1s[t] = b1[t]; g1s[t] = g1[t]; be1s[t] = be1[t]; }
  __syncthreads();
  int i = blockIdx.x * 256 + t;
  if (i >= NN) return;
  const float2* xs2 = (const float2*)xs;
  float2 sv = xs2[i];
  float in0 = sv.x, in1 = sv.y;           // self term (xs already has dinv)
  int r0 = rowptr[i], dg = deg[i];
  int k = 0;
  for (; k + 4 <= dg; k += 4) {           // 4 independent loads, ordered adds
    int s0 = csr[r0 + k], s1 = csr[r0 + k + 1];
    int s2 = csr[r0 + k + 2], s3 = csr[r0 + k + 3];
    float2 v0 = xs2[s0], v1 = xs2[s1], v2 = xs2[s2], v3 = xs2[s3];
    in0 += v0.x; in1 += v0.y;
    in0 += v1.x; in1 += v1.y;
    in0 += v2.x; in1 += v2.y;
    in0 += v3.x; in1 += v3.y;
  }
  for (; k < dg; k++) {
    int s = csr[r0 + k];
    float2 v = xs2[s];
    in0 += v.x; in1 += v.y;
  }
  float di = dinv[i];
  float a0 = di * in0, a1 = di * in1;
  float h[HID];
  float mu = 0.f;
#pragma unroll
  for (int j = 0; j < HID; j++) {
    h[j] = fmaf(a0, w1s[j], fmaf(a1, w1s[32 + j], b1s[j]));
    mu += h[j];
  }
  mu *= (1.0f / HID);
  float var = 0.f;
#pragma unroll
  for (int j = 0; j < HID; j++) { float dd = h[j] - mu; var += dd * dd; }
  var *= (1.0f / HID);
  float rstd = rsqrtf(var + 1e-5f);
  float4* o4 = (float4*)(h1s + (size_t)i * HID);
#pragma unroll
  for (int q = 0; q < 8; q++) {
    float4 v;
    v.x = di * fmaxf(fmaf((h[4 * q]     - mu) * rstd, g1s[4 * q],     be1s[4 * q]),     0.f);
    v.y = di * fmaxf(fmaf((h[4 * q + 1] - mu) * rstd, g1s[4 * q + 1], be1s[4 * q + 1]), 0.f);
    v.z = di * fmaxf(fmaf((h[4 * q + 2] - mu) * rstd, g1s[4 * q + 2], be1s[4 * q + 2]), 0.f);
    v.w = di * fmaxf(fmaf((h[4 * q + 3] - mu) * rstd, g1s[4 * q + 3], be1s[4 * q + 3]), 0.f);
    o4[q] = v;
  }
}

// layer 2: 32 lanes = one node; 8 nodes/block -> 12500 blocks.
// CSR indices coalesced per-lane, broadcast via shfl. Edge loop runs in
// wave-uniform 8-tiles, fully unrolled: pad lanes use index NN -> zero row,
// so 8 independent loads issue back-to-back (latency overlapped) while the
// real-entry summation order is unchanged (padded adds are exactly +0.0f).
// Writes ps = dinv[i] * p[i] (premult for layer 3).
__global__ __launch_bounds__(256) void k_l2(const int* __restrict__ rowptr,
                                            const int* __restrict__ deg,
                                            const int* __restrict__ csr,
                                            const float* __restrict__ dinv,
                                            const float* __restrict__ h1s,
                                            const float* __restrict__ w2,
                                            const float* __restrict__ b2,
                                            const float* __restrict__ g2,
                                            const float* __restrict__ be2,
                                            const float* __restrict__ w3,
                                            float* __restrict__ ps) {
  __shared__ float w2s[HID * HID];
  __shared__ float b2s[32], g2s[32], be2s[32], w3s[32];
  int t = threadIdx.x;
  for (int u = t; u < HID * HID; u += 256) w2s[u] = w2[u];
  if (t < 32) { b2s[t] = b2[t]; g2s[t] = g2[t]; be2s[t] = be2[t]; w3s[t] = w3[t]; }
  __syncthreads();
  int i = blockIdx.x * 8 + (t >> 5);   // node (grid exact: 12500*8 == NN)
  int f = t & 31;                      // feature lane
  float acc = h1s[(size_t)i * HID + f];     // self term (premultiplied)
  int r0 = rowptr[i], dg = deg[i];
  for (int base = 0; base < dg; base += 32) {
    int kk = base + f;
    int idx = (kk < dg) ? csr[r0 + kk] : NN;  // pad -> zero row
    int rem = dg - base;                       // uniform across group
    int ntile = min(rem, 32);
    for (int sub = 0; sub < ntile; sub += 8) { // uniform trip count
#pragma unroll
      for (int j = 0; j < 8; j++) {
        int s = __shfl(idx, sub + j, 32);
        acc += h1s[(size_t)s * HID + f];       // 8 loads in flight per tile
      }
    }
  }
  float di = dinv[i];
  acc *= di;                           // agg2[i,f]
  float h = b2s[f];
#pragma unroll
  for (int k = 0; k < HID; k++) {
    float ak = __shfl(acc, k, 32);
    h = fmaf(ak, w2s[k * HID + f], h);
  }
  float mu = h;
#pragma unroll
  for (int off = 16; off > 0; off >>= 1) mu += __shfl_xor(mu, off, 32);
  mu *= (1.0f / HID);
  float dd = h - mu;
  float var = dd * dd;
#pragma unroll
  for (int off = 16; off > 0; off >>= 1) var += __shfl_xor(var, off, 32);
  var *= (1.0f / HID);
  float rstd = rsqrtf(var + 1e-5f);
  float v = fmaf(dd * rstd, g2s[f], be2s[f]);
  v = fmaxf(v, 0.0f);
  float pi = v * w3s[f];
#pragma unroll
  for (int off = 16; off > 0; off >>= 1) pi += __shfl_xor(pi, off, 32);
  if (f == 0) ps[i] = di * pi;
}

// layer 3: per-node thread, 4x-batched sum of premultiplied ps
__global__ __launch_bounds__(256) void k_l3(const int* __restrict__ rowptr,
                                            const int* __restrict__ deg,
                                            const int* __restrict__ csr,
                                            const float* __restrict__ dinv,
                                            const float* __restrict__ ps,
                                            const float* __restrict__ b3,
                                            float* __restrict__ out) {
  int i = blockIdx.x * 256 + threadIdx.x;
  if (i >= NN) return;
  float inner = ps[i];                 // self term (premultiplied)
  int r0 = rowptr[i], dg = deg[i];
  int k = 0;
  for (; k + 4 <= dg; k += 4) {
    float v0 = ps[csr[r0 + k]],     v1 = ps[csr[r0 + k + 1]];
    float v2 = ps[csr[r0 + k + 2]], v3 = ps[csr[r0 + k + 3]];
    inner += v0; inner += v1; inner += v2; inner += v3;
  }
  for (; k < dg; k++) inner += ps[csr[r0 + k]];
  out[i] = fmaf(dinv[i], inner, b3[0]);
}

// ---------------- launch ----------------

extern "C" void kernel_launch(void* const* d_in, const int* in_sizes, int n_in,
                              void* d_out, int out_size, void* d_ws, size_t ws_size,
                              hipStream_t stream) {
  const float* x   = (const float*)d_in[0];
  const int*   ei  = (const int*)d_in[1];
  const float* w1  = (const float*)d_in[2];
  const float* b1  = (const float*)d_in[3];
  const float* g1  = (const float*)d_in[4];
  const float* be1 = (const float*)d_in[5];
  const float* w2  = (const float*)d_in[6];
  const float* b2  = (const float*)d_in[7];
  const float* g2  = (const float*)d_in[8];
  const float* be2 = (const float*)d_in[9];
  const float* w3  = (const float*)d_in[10];
  const float* b3  = (const float*)d_in[11];
  float* out = (float*)d_out;

  char* wp = (char*)d_ws;
  auto alloc = [&](size_t bytes) {
    char* r = wp;
    wp += (bytes + 255) & ~size_t(255);
    return r;
  };
  int*   bincnt = (int*)alloc((size_t)NBIN * 4);
  int*   binptr = (int*)alloc((size_t)(NBIN + 1) * 4);
  int*   cursor = (int*)alloc((size_t)NBIN * 4);
  int*   bedge  = (int*)alloc((size_t)NE * 4);
  int*   csr    = (int*)alloc((size_t)NE * 4);
  int*   rowptr = (int*)alloc((size_t)NN * 4);
  int*   deg    = (int*)alloc((size_t)NN * 4);
  float* dinv   = (float*)alloc((size_t)NN * 4);
  float* xs     = (float*)alloc((size_t)NN * 2 * 4);
  float* h1s    = (float*)alloc((size_t)(NN + 1) * HID * 4);  // +1 zero pad row
  float* ps     = (float*)alloc((size_t)NN * 4);

  hipMemsetAsync(bincnt, 0, (size_t)NBIN * 4, stream);
  hipMemsetAsync(h1s + (size_t)NN * HID, 0, HID * 4, stream);  // zero pad row
  k_binhist  <<<NB, 256, 0, stream>>>(ei, bincnt);
  k_binscan  <<<1, 1024, 0, stream>>>(bincnt, binptr, cursor);
  k_wcscatter<<<NCHUNK * NPART, 256, 0, stream>>>(ei, cursor, bedge);
  k_sort     <<<NBIN, 256, 0, stream>>>(binptr, bedge, x, csr, rowptr, deg, dinv, xs);
  k_l1       <<<NB, 256, 0, stream>>>(rowptr, deg, csr, dinv, xs, w1, b1, g1, be1, h1s);
  k_l2       <<<NN / 8, 256, 0, stream>>>(rowptr, deg, csr, dinv, h1s,
                                          w2, b2, g2, be2, w3, ps);
  k_l3       <<<NB, 256, 0, stream>>>(rowptr, deg, csr, dinv, ps, b3, out);
}

// Round 12
// 222.675 us; speedup vs baseline: 4.1094x; 1.0776x over previous
//
#include <hip/hip_runtime.h>

constexpr int NN  = 100000;   // nodes
constexpr int NE  = 1600000;  // edges
constexpr int NE4 = NE / 4;   // edge quads
constexpr int HID = 32;
constexpr int NPB = 128;                      // nodes per bucket (= 1<<7)
constexpr int NBIN = (NN + NPB - 1) / NPB;    // 782 buckets
constexpr int NB  = (NN + 255) / 256;         // 391

constexpr int NPART = 8;                      // XCD partitions
constexpr int PPB   = (NBIN + NPART - 1) / NPART;  // 98 buckets per partition
constexpr int NCHUNK = 120;                   // edge chunks (grid = 960)
constexpr int CAP   = 16;                     // queue entries = 64B flush chunk
constexpr int QS    = CAP + 1;                // padded stride (bank spread)

// ---------------- build: bucket scatter + per-bucket counting sort ----------------

__global__ __launch_bounds__(256) void k_binhist(const int* __restrict__ ei,
                                                 int* __restrict__ bincnt) {
  __shared__ int lh[NBIN];
  int t = threadIdx.x;
  for (int b = t; b < NBIN; b += 256) lh[b] = 0;
  __syncthreads();
  const int4* d4 = (const int4*)(ei + NE);
  for (int q = blockIdx.x * 256 + t; q < NE4; q += gridDim.x * 256) {
    int4 v = d4[q];
    atomicAdd(&lh[v.x >> 7], 1);
    atomicAdd(&lh[v.y >> 7], 1);
    atomicAdd(&lh[v.z >> 7], 1);
    atomicAdd(&lh[v.w >> 7], 1);
  }
  __syncthreads();
  for (int b = t; b < NBIN; b += 256) {
    int v = lh[b];
    if (v) atomicAdd(&bincnt[b], v);
  }
}

__global__ __launch_bounds__(1024) void k_binscan(const int* __restrict__ bincnt,
                                                  int* __restrict__ binptr,
                                                  int* __restrict__ cursor) {
  __shared__ int s[1024];
  int t = threadIdx.x;
  int v = (t < NBIN) ? bincnt[t] : 0;
  s[t] = v;
  __syncthreads();
#pragma unroll
  for (int off = 1; off < 1024; off <<= 1) {
    int add = (t >= off) ? s[t - off] : 0;
    __syncthreads();
    s[t] += add;
    __syncthreads();
  }
  if (t < NBIN) {
    int ex = s[t] - v;
    binptr[t] = ex;
    cursor[t] = ex;
  }
  if (t == NBIN - 1) binptr[NBIN] = s[t];
}

// LDS write-combining scatter, 4-edge coarsened; src loaded as int4
__global__ __launch_bounds__(256) void k_wcscatter(const int* __restrict__ ei,
                                                   int* __restrict__ cursor,
                                                   int* __restrict__ be) {
  __shared__ int q[PPB * QS];
  __shared__ int qn[PPB];
  int t = threadIdx.x;
  int part  = blockIdx.x & (NPART - 1);
  int chunk = blockIdx.x >> 3;
  int b0  = part * PPB;
  int bHi = min(b0 + PPB, NBIN);
  int nb  = bHi - b0;
  for (int b = t; b < nb; b += 256) qn[b] = 0;
  int q0 = (int)((long long)NE4 * chunk / NCHUNK);
  int q1 = (int)((long long)NE4 * (chunk + 1) / NCHUNK);
  const int4* d4 = (const int4*)(ei + NE);
  const int4* s4 = (const int4*)ei;
  __syncthreads();
  for (int qbase = q0; qbase < q1; qbase += 256) {
    int qi = qbase + t;
    int4 dv = make_int4(-1, -1, -1, -1);
    int4 sv = make_int4(0, 0, 0, 0);
    if (qi < q1) { dv = d4[qi]; sv = s4[qi]; }
    int val0 = 0, val1 = 0, val2 = 0, val3 = 0;
    int lb0 = 0, lb1 = 0, lb2 = 0, lb3 = 0;
    unsigned pend = 0;
    {
      int bkt = dv.x >> 7;
      if (dv.x >= 0 && bkt >= b0 && bkt < bHi) {
        val0 = sv.x | ((dv.x & (NPB - 1)) << 17);
        lb0 = bkt - b0;
        int slot = atomicAdd(&qn[lb0], 1);
        if (slot < CAP) q[lb0 * QS + slot] = val0; else pend |= 1u;
      }
    }
    {
      int bkt = dv.y >> 7;
      if (dv.y >= 0 && bkt >= b0 && bkt < bHi) {
        val1 = sv.y | ((dv.y & (NPB - 1)) << 17);
        lb1 = bkt - b0;
        int slot = atomicAdd(&qn[lb1], 1);
        if (slot < CAP) q[lb1 * QS + slot] = val1; else pend |= 2u;
      }
    }
    {
      int bkt = dv.z >> 7;
      if (dv.z >= 0 && bkt >= b0 && bkt < bHi) {
        val2 = sv.z | ((dv.z & (NPB - 1)) << 17);
        lb2 = bkt - b0;
        int slot = atomicAdd(&qn[lb2], 1);
        if (slot < CAP) q[lb2 * QS + slot] = val2; else pend |= 4u;
      }
    }
    {
      int bkt = dv.w >> 7;
      if (dv.w >= 0 && bkt >= b0 && bkt < bHi) {
        val3 = sv.w | ((dv.w & (NPB - 1)) << 17);
        lb3 = bkt - b0;
        int slot = atomicAdd(&qn[lb3], 1);
        if (slot < CAP) q[lb3 * QS + slot] = val3; else pend |= 8u;
      }
    }
    for (;;) {
      __syncthreads();
      for (int b = t; b < nb; b += 256) {
        int n = qn[b];
        if (n >= CAP) {
          int pos = atomicAdd(&cursor[b0 + b], CAP);
#pragma unroll
          for (int j = 0; j < CAP; j++) be[pos + j] = q[b * QS + j];
          qn[b] = 0;
        }
      }
      if (!__syncthreads_or(pend ? 1 : 0)) break;
      if (pend & 1u) {
        int slot = atomicAdd(&qn[lb0], 1);
        if (slot < CAP) { q[lb0 * QS + slot] = val0; pend &= ~1u; }
      }
      if (pend & 2u) {
        int slot = atomicAdd(&qn[lb1], 1);
        if (slot < CAP) { q[lb1 * QS + slot] = val1; pend &= ~2u; }
      }
      if (pend & 4u) {
        int slot = atomicAdd(&qn[lb2], 1);
        if (slot < CAP) { q[lb2 * QS + slot] = val2; pend &= ~4u; }
      }
      if (pend & 8u) {
        int slot = atomicAdd(&qn[lb3], 1);
        if (slot < CAP) { q[lb3 * QS + slot] = val3; pend &= ~8u; }
      }
    }
  }
  for (int b = t; b < nb; b += 256) {
    int n = qn[b];
    if (n > 0) {
      int pos = atomicAdd(&cursor[b0 + b], n);
      for (int j = 0; j < n; j++) be[pos + j] = q[b * QS + j];
    }
  }
}

// per-bucket counting sort -> CSR + deg + rowptr + dinv + xs (= dinv*x premult)
__global__ __launch_bounds__(256) void k_sort(const int* __restrict__ binptr,
                                              const int* __restrict__ be,
                                              const float* __restrict__ x,
                                              int* __restrict__ csr,
                                              int* __restrict__ rowptr,
                                              int* __restrict__ deg,
                                              float* __restrict__ dinv,
                                              float* __restrict__ xs) {
  __shared__ int hist[NPB];
  __shared__ int excl[NPB];
  __shared__ int cur[NPB];
  int t = threadIdx.x, b = blockIdx.x;
  int e0 = binptr[b], e1 = binptr[b + 1];
  if (t < NPB) hist[t] = 0;
  __syncthreads();
  for (int k = e0 + t; k < e1; k += 256) atomicAdd(&hist[be[k] >> 17], 1);
  __syncthreads();
  if (t < NPB) excl[t] = hist[t];
  __syncthreads();
#pragma unroll
  for (int off = 1; off < NPB; off <<= 1) {
    int add = 0;
    if (t < NPB && t >= off) add = excl[t - off];
    __syncthreads();
    if (t < NPB) excl[t] += add;
    __syncthreads();
  }
  if (t < NPB) {
    int ex = excl[t] - hist[t];
    cur[t] = ex;
    int i = b * NPB + t;
    if (i < NN) {
      int dg = hist[t];
      deg[i] = dg;
      rowptr[i] = e0 + ex;
      float d = rsqrtf((float)dg + 1.0f);
      dinv[i] = d;
      float2 xv = ((const float2*)x)[i];
      ((float2*)xs)[i] = make_float2(d * xv.x, d * xv.y);
    }
  }
  __syncthreads();
  for (int k = e0 + t; k < e1; k += 256) {
    int v = be[k];
    int pos = atomicAdd(&cur[v >> 17], 1);
    csr[e0 + pos] = v & 0x1FFFF;
  }
}

// ---------------- layers (premultiplied operands) ----------------

// layer 1: per-node thread, 4x-batched gather of xs (order-preserving ILP).
// Writes h1s = di * relu(LN(...))  (premultiplied for layer 2)
__global__ __launch_bounds__(256) void k_l1(const int* __restrict__ rowptr,
                                            const int* __restrict__ deg,
                                            const int* __restrict__ csr,
                                            const float* __restrict__ dinv,
                                            const float* __restrict__ xs,
                                            const float* __restrict__ w1,
                                            const float* __restrict__ b1,
                                            const float* __restrict__ g1,
                                            const float* __restrict__ be1,
                                            float* __restrict__ h1s) {
  __shared__ float w1s[64], b1s[32], g1s[32], be1s[32];
  int t = threadIdx.x;
  if (t < 64) w1s[t] = w1[t];
  if (t < 32) { b1s[t] = b1[t]; g1s[t] = g1[t]; be1s[t] = be1[t]; }
  __syncthreads();
  int i = blockIdx.x * 256 + t;
  if (i >= NN) return;
  const float2* xs2 = (const float2*)xs;
  float2 sv = xs2[i];
  float in0 = sv.x, in1 = sv.y;           // self term (xs already has dinv)
  int r0 = rowptr[i], dg = deg[i];
  int k = 0;
  for (; k + 4 <= dg; k += 4) {           // 4 independent loads, ordered adds
    int s0 = csr[r0 + k], s1 = csr[r0 + k + 1];
    int s2 = csr[r0 + k + 2], s3 = csr[r0 + k + 3];
    float2 v0 = xs2[s0], v1 = xs2[s1], v2 = xs2[s2], v3 = xs2[s3];
    in0 += v0.x; in1 += v0.y;
    in0 += v1.x; in1 += v1.y;
    in0 += v2.x; in1 += v2.y;
    in0 += v3.x; in1 += v3.y;
  }
  for (; k < dg; k++) {
    int s = csr[r0 + k];
    float2 v = xs2[s];
    in0 += v.x; in1 += v.y;
  }
  float di = dinv[i];
  float a0 = di * in0, a1 = di * in1;
  float h[HID];
  float mu = 0.f;
#pragma unroll
  for (int j = 0; j < HID; j++) {
    h[j] = fmaf(a0, w1s[j], fmaf(a1, w1s[32 + j], b1s[j]));
    mu += h[j];
  }
  mu *= (1.0f / HID);
  float var = 0.f;
#pragma unroll
  for (int j = 0; j < HID; j++) { float dd = h[j] - mu; var += dd * dd; }
  var *= (1.0f / HID);
  float rstd = rsqrtf(var + 1e-5f);
  float4* o4 = (float4*)(h1s + (size_t)i * HID);
#pragma unroll
  for (int q = 0; q < 8; q++) {
    float4 v;
    v.x = di * fmaxf(fmaf((h[4 * q]     - mu) * rstd, g1s[4 * q],     be1s[4 * q]),     0.f);
    v.y = di * fmaxf(fmaf((h[4 * q + 1] - mu) * rstd, g1s[4 * q + 1], be1s[4 * q + 1]), 0.f);
    v.z = di * fmaxf(fmaf((h[4 * q + 2] - mu) * rstd, g1s[4 * q + 2], be1s[4 * q + 2]), 0.f);
    v.w = di * fmaxf(fmaf((h[4 * q + 3] - mu) * rstd, g1s[4 * q + 3], be1s[4 * q + 3]), 0.f);
    o4[q] = v;
  }
}

// layer 2: 32 lanes = one node; 8 nodes/block -> 12500 blocks.
// Lane L = (edge-slot jg = L>>3, feature-quad c4 = L&7). Per 4 edges:
// broadcast csr read (same addr for the 8 lanes of a jg) + select-to-pad +
// one float4 gather (8 lanes x 16B = full 128B row) + 4 adds. Tail lanes use
// row NN (zeros). Cross-slot reduce via shfl_xor 8/16 (same c4); jg==0 lanes
// stage agg in LDS; matvec reads uniform broadcasts.
// Writes ps = dinv[i] * p[i] (premult for layer 3).
__global__ __launch_bounds__(256) void k_l2(const int* __restrict__ rowptr,
                                            const int* __restrict__ deg,
                                            const int* __restrict__ csr,
                                            const float* __restrict__ dinv,
                                            const float* __restrict__ h1s,
                                            const float* __restrict__ w2,
                                            const float* __restrict__ b2,
                                            const float* __restrict__ g2,
                                            const float* __restrict__ be2,
                                            const float* __restrict__ w3,
                                            float* __restrict__ ps) {
  __shared__ float w2s[HID * HID];
  __shared__ float b2s[32], g2s[32], be2s[32], w3s[32];
  __shared__ float aggl[8][HID];
  int t = threadIdx.x;
  for (int u = t; u < HID * HID; u += 256) w2s[u] = w2[u];
  if (t < 32) { b2s[t] = b2[t]; g2s[t] = g2[t]; be2s[t] = be2[t]; w3s[t] = w3[t]; }
  __syncthreads();
  int g = t >> 5;
  int L = t & 31;
  int i = blockIdx.x * 8 + g;          // node (grid exact: 12500*8 == NN)
  int jg = L >> 3, c4 = L & 7;
  const float4* h4 = (const float4*)h1s;
  float ax = 0.f, ay = 0.f, az = 0.f, aw = 0.f;
  if (jg == 0) {                        // self row once (premultiplied)
    float4 v = h4[(size_t)i * 8 + c4];
    ax += v.x; ay += v.y; az += v.z; aw += v.w;
  }
  int r0 = rowptr[i], dg = deg[i];
  for (int base = 0; base < dg; base += 16) {
#pragma unroll
    for (int it = 0; it < 4; it++) {
      int kk = base + it * 4 + jg;
      int sv = csr[r0 + kk];            // csr has +32 slack; over-reads safe
      int s = (kk < dg) ? sv : NN;      // pad -> zero row
      float4 v = h4[(size_t)s * 8 + c4];
      ax += v.x; ay += v.y; az += v.z; aw += v.w;
    }
  }
  // reduce across the 4 edge-slots (lanes jg*8+c4: xor 8 and xor 16 keep c4)
  ax += __shfl_xor(ax, 8, 32);  ay += __shfl_xor(ay, 8, 32);
  az += __shfl_xor(az, 8, 32);  aw += __shfl_xor(aw, 8, 32);
  ax += __shfl_xor(ax, 16, 32); ay += __shfl_xor(ay, 16, 32);
  az += __shfl_xor(az, 16, 32); aw += __shfl_xor(aw, 16, 32);
  float di = dinv[i];
  if (jg == 0) {
    aggl[g][c4 * 4 + 0] = di * ax;
    aggl[g][c4 * 4 + 1] = di * ay;
    aggl[g][c4 * 4 + 2] = di * az;
    aggl[g][c4 * 4 + 3] = di * aw;
  }
  __syncthreads();
  // matvec: h[f] = b2[f] + sum_k agg[k] * w2[k][f]
  float h = b2s[L];
#pragma unroll
  for (int k = 0; k < HID; k++) h = fmaf(aggl[g][k], w2s[k * HID + L], h);
  float mu = h;
#pragma unroll
  for (int off = 16; off > 0; off >>= 1) mu += __shfl_xor(mu, off, 32);
  mu *= (1.0f / HID);
  float dd = h - mu;
  float var = dd * dd;
#pragma unroll
  for (int off = 16; off > 0; off >>= 1) var += __shfl_xor(var, off, 32);
  var *= (1.0f / HID);
  float rstd = rsqrtf(var + 1e-5f);
  float v = fmaf(dd * rstd, g2s[L], be2s[L]);
  v = fmaxf(v, 0.0f);
  float pi = v * w3s[L];
#pragma unroll
  for (int off = 16; off > 0; off >>= 1) pi += __shfl_xor(pi, off, 32);
  if (L == 0) ps[i] = di * pi;
}

// layer 3: per-node thread, 4x-batched sum of premultiplied ps
__global__ __launch_bounds__(256) void k_l3(const int* __restrict__ rowptr,
                                            const int* __restrict__ deg,
                                            const int* __restrict__ csr,
                                            const float* __restrict__ dinv,
                                            const float* __restrict__ ps,
                                            const float* __restrict__ b3,
                                            float* __restrict__ out) {
  int i = blockIdx.x * 256 + threadIdx.x;
  if (i >= NN) return;
  float inner = ps[i];                 // self term (premultiplied)
  int r0 = rowptr[i], dg = deg[i];
  int k = 0;
  for (; k + 4 <= dg; k += 4) {
    float v0 = ps[csr[r0 + k]],     v1 = ps[csr[r0 + k + 1]];
    float v2 = ps[csr[r0 + k + 2]], v3 = ps[csr[r0 + k + 3]];
    inner += v0; inner += v1; inner += v2; inner += v3;
  }
  for (; k < dg; k++) inner += ps[csr[r0 + k]];
  out[i] = fmaf(dinv[i], inner, b3[0]);
}

// ---------------- launch ----------------

extern "C" void kernel_launch(void* const* d_in, const int* in_sizes, int n_in,
                              void* d_out, int out_size, void* d_ws, size_t ws_size,
                              hipStream_t stream) {
  const float* x   = (const float*)d_in[0];
  const int*   ei  = (const int*)d_in[1];
  const float* w1  = (const float*)d_in[2];
  const float* b1  = (const float*)d_in[3];
  const float* g1  = (const float*)d_in[4];
  const float* be1 = (const float*)d_in[5];
  const float* w2  = (const float*)d_in[6];
  const float* b2  = (const float*)d_in[7];
  const float* g2  = (const float*)d_in[8];
  const float* be2 = (const float*)d_in[9];
  const float* w3  = (const float*)d_in[10];
  const float* b3  = (const float*)d_in[11];
  float* out = (float*)d_out;

  char* wp = (char*)d_ws;
  auto alloc = [&](size_t bytes) {
    char* r = wp;
    wp += (bytes + 255) & ~size_t(255);
    return r;
  };
  int*   bincnt = (int*)alloc((size_t)NBIN * 4);
  int*   binptr = (int*)alloc((size_t)(NBIN + 1) * 4);
  int*   cursor = (int*)alloc((size_t)NBIN * 4);
  int*   bedge  = (int*)alloc((size_t)NE * 4);
  int*   csr    = (int*)alloc((size_t)(NE + 32) * 4);       // +32 slack for k_l2 over-read
  int*   rowptr = (int*)alloc((size_t)NN * 4);
  int*   deg    = (int*)alloc((size_t)NN * 4);
  float* dinv   = (float*)alloc((size_t)NN * 4);
  float* xs     = (float*)alloc((size_t)NN * 2 * 4);
  float* h1s    = (float*)alloc((size_t)(NN + 1) * HID * 4);  // +1 zero pad row
  float* ps     = (float*)alloc((size_t)NN * 4);

  hipMemsetAsync(bincnt, 0, (size_t)NBIN * 4, stream);
  hipMemsetAsync(h1s + (size_t)NN * HID, 0, HID * 4, stream);  // zero pad row
  k_binhist  <<<NB, 256, 0, stream>>>(ei, bincnt);
  k_binscan  <<<1, 1024, 0, stream>>>(bincnt, binptr, cursor);
  k_wcscatter<<<NCHUNK * NPART, 256, 0, stream>>>(ei, cursor, bedge);
  k_sort     <<<NBIN, 256, 0, stream>>>(binptr, bedge, x, csr, rowptr, deg, dinv, xs);
  k_l1       <<<NB, 256, 0, stream>>>(rowptr, deg, csr, dinv, xs, w1, b1, g1, be1, h1s);
  k_l2       <<<NN / 8, 256, 0, stream>>>(rowptr, deg, csr, dinv, h1s,
                                          w2, b2, g2, be2, w3, ps);
  k_l3       <<<NB, 256, 0, stream>>>(rowptr, deg, csr, dinv, ps, b3, out);
}